// Round 13
// baseline (185.186 us; speedup 1.0000x reference)
//
#include <hip/hip_runtime.h>
#include <hip/hip_bf16.h>

// ---------- types ----------
typedef __attribute__((ext_vector_type(8))) short bf16x8;   // 8 bf16 in 4 VGPRs
typedef __attribute__((ext_vector_type(4))) short bf16x4;   // 4 bf16 in 2 VGPRs
typedef __attribute__((ext_vector_type(4))) float f32x4;
typedef __attribute__((ext_vector_type(4))) int   i32x4;

#define C2LOG 0.18033688011112042f   // 0.125 * log2(e): folds 1/sqrt(64) + base-2
#define THR_RAW 44.3616f             // 8 / C2LOG : defer-max threshold (raw units)

// fp32 -> bf16 round-to-nearest-even (scalar)
__device__ __forceinline__ short f2bf(float f) {
    union { float f; unsigned u; } v; v.f = f;
    unsigned r = v.u + 0x7fff + ((v.u >> 16) & 1);
    return (short)(r >> 16);
}
// HW packed conversion: 2 fp32 -> u32 of 2 bf16 (RNE), one instruction
__device__ __forceinline__ unsigned cvtpk(float lo, float hi) {
    unsigned r;
    asm("v_cvt_pk_bf16_f32 %0, %1, %2" : "=v"(r) : "v"(lo), "v"(hi));
    return r;
}
__device__ __forceinline__ float bf2f(short s) {
    union { unsigned u; float f; } v; v.u = ((unsigned)(unsigned short)s) << 16;
    return v.f;
}

// ---------- sizes ----------
#define BB 4
#define TT 4096
#define CC 1024
#define HD 64
#define NTASK_PB 144          // tasks per batch: sum_{g=0}^{7} 4*(g+1) = 144  (R9 split)
#define NTASK (BB * NTASK_PB) // 576

// =====================================================================
// Kernel 1: pack W q/k/v -> transposed bf16 Wt[192][1024], COALESCED
// (LDS transpose, pad 65).
// =====================================================================
__global__ __launch_bounds__(256) void prep_w(const float* __restrict__ Wq,
        const float* __restrict__ Wk, const float* __restrict__ Wv,
        short* __restrict__ Wt) {
    __shared__ float wls[64][65];
    const int w = blockIdx.x >> 4;            // 0..2
    const int c = blockIdx.x & 15;            // k-chunk
    const float* W = (w == 0) ? Wq : (w == 1) ? Wk : Wv;

    const int r  = threadIdx.x >> 4;          // 0..15
    const int q4 = threadIdx.x & 15;          // float4 col
    #pragma unroll
    for (int rr = 0; rr < 4; ++rr) {
        const int row = rr * 16 + r;          // 0..63 (k-local)
        float4 v = *reinterpret_cast<const float4*>(
            W + (size_t)(c * 64 + row) * HD + q4 * 4);
        wls[row][q4 * 4 + 0] = v.x;
        wls[row][q4 * 4 + 1] = v.y;
        wls[row][q4 * 4 + 2] = v.z;
        wls[row][q4 * 4 + 3] = v.w;
    }
    __syncthreads();

    const int n  = threadIdx.x >> 2;          // 0..63 (output row within W)
    const int ks = (threadIdx.x & 3) * 16;    // k-offset within chunk
    bf16x8 o0, o1;
    #pragma unroll
    for (int j = 0; j < 8; ++j) o0[j] = f2bf(wls[ks + j][n]);
    #pragma unroll
    for (int j = 0; j < 8; ++j) o1[j] = f2bf(wls[ks + 8 + j][n]);
    short* dst = Wt + (size_t)(w * 64 + n) * CC + c * 64 + ks;
    *reinterpret_cast<bf16x8*>(dst)     = o0;
    *reinterpret_cast<bf16x8*>(dst + 8) = o1;
}

// =====================================================================
// Kernel 2: QKV projection (R9 proven version: xs LDS staging + W DMA
// double-buffer, one vmcnt(0)+barrier per K-chunk).
// =====================================================================
__global__ __launch_bounds__(512) void proj_qkv(const float* __restrict__ x,
        const short* __restrict__ Wt, short* __restrict__ Q,
        short* __restrict__ K, short* __restrict__ Vt) {
    __shared__ short xs[2][32 * 72];      // x tile bf16, pad-72 (reg-staged)
    __shared__ short wsm[2][192 * 64];    // W chunk bf16, 128B rows, XOR-swizzled

    const int tid  = threadIdx.x;
    const int lane = tid & 63;
    const int wv   = tid >> 6;
    const int lm   = lane & 15;
    const int lg   = lane >> 4;
    const int mhalf = wv & 1;
    const int ngrp  = wv >> 1;
    const int mbase = blockIdx.x * 32;

    const int xr  = tid >> 4;             // 0..31
    const int xq4 = tid & 15;             // float4 index within chunk
    const float* xrow = x + (size_t)(mbase + xr) * CC;

    int wsrow[3], wscol[3];
    #pragma unroll
    for (int it = 0; it < 3; ++it) {
        const int off = it * 8192 + wv * 1024 + lane * 16;
        wsrow[it] = off >> 7;
        wscol[it] = (off & 127) ^ ((wsrow[it] & 7) << 4);
    }

#define STAGE_W(bufidx, kc)                                                           \
    {                                                                                 \
        _Pragma("unroll")                                                             \
        for (int it = 0; it < 3; ++it) {                                              \
            const char* src = (const char*)(Wt + (size_t)wsrow[it] * CC + (kc) * 64)  \
                              + wscol[it];                                            \
            char* dst = (char*)&wsm[bufidx][0] + it * 8192 + wv * 1024;               \
            __builtin_amdgcn_global_load_lds(                                         \
                (const __attribute__((address_space(1))) unsigned*)src,               \
                (__attribute__((address_space(3))) unsigned*)dst, 16, 0, 0);          \
        }                                                                             \
    }

#define CONV_X(bufidx, xv)                                                            \
    {                                                                                 \
        int2 pk;                                                                      \
        pk.x = (int)cvtpk((xv).x, (xv).y);                                            \
        pk.y = (int)cvtpk((xv).z, (xv).w);                                            \
        *reinterpret_cast<int2*>(&xs[bufidx][xr * 72 + xq4 * 4]) = pk;                \
    }

    f32x4 acc[3];
    #pragma unroll
    for (int i = 0; i < 3; ++i) acc[i] = f32x4{0.f, 0.f, 0.f, 0.f};

    {
        float4 v = *reinterpret_cast<const float4*>(xrow + xq4 * 4);
        CONV_X(0, v)
        STAGE_W(0, 0)
    }
    asm volatile("s_waitcnt vmcnt(0)" ::: "memory");
    __syncthreads();

    const int arow = mhalf * 16 + lm;
    int buf = 0;
    for (int kc = 0; kc < 16; ++kc) {
        float4 nv;
        const bool more = (kc < 15);
        if (more) {
            nv = *reinterpret_cast<const float4*>(xrow + (kc + 1) * 64 + xq4 * 4);
            STAGE_W(buf ^ 1, kc + 1)
        }

        bf16x8 a0 = *reinterpret_cast<const bf16x8*>(&xs[buf][arow * 72 + lg * 8]);
        bf16x8 a1 = *reinterpret_cast<const bf16x8*>(&xs[buf][arow * 72 + 32 + lg * 8]);
        #pragma unroll
        for (int c = 0; c < 3; ++c) {
            const int brow = (ngrp * 3 + c) * 16 + lm;
            const int sw = (brow & 7) << 4;
            bf16x8 b0 = *reinterpret_cast<const bf16x8*>(
                (const char*)&wsm[buf][0] + brow * 128 + ((lg * 16) ^ sw));
            bf16x8 b1 = *reinterpret_cast<const bf16x8*>(
                (const char*)&wsm[buf][0] + brow * 128 + ((64 + lg * 16) ^ sw));
            acc[c] = __builtin_amdgcn_mfma_f32_16x16x32_bf16(a0, b0, acc[c], 0, 0, 0);
            acc[c] = __builtin_amdgcn_mfma_f32_16x16x32_bf16(a1, b1, acc[c], 0, 0, 0);
        }

        if (more) CONV_X(buf ^ 1, nv)
        asm volatile("s_waitcnt vmcnt(0)" ::: "memory");
        __syncthreads();
        buf ^= 1;
    }
#undef STAGE_W
#undef CONV_X

    const int mrow = mbase + mhalf * 16 + lg * 4;
    #pragma unroll
    for (int c = 0; c < 3; ++c) {
        const int cn = ngrp * 3 + c;
        if (cn < 4) {
            #pragma unroll
            for (int r = 0; r < 4; ++r)
                Q[(size_t)(mrow + r) * HD + cn * 16 + lm] = f2bf(acc[c][r]);
        } else if (cn < 8) {
            #pragma unroll
            for (int r = 0; r < 4; ++r)
                K[(size_t)(mrow + r) * HD + (cn - 4) * 16 + lm] = f2bf(acc[c][r]);
        } else {
            const int bb   = mbase >> 12;
            const int tloc = (mbase & 4095) + mhalf * 16 + lg * 4;
            int2 pk;
            pk.x = (int)cvtpk(acc[c][0], acc[c][1]);
            pk.y = (int)cvtpk(acc[c][2], acc[c][3]);
            *reinterpret_cast<int2*>(
                Vt + (size_t)bb * (HD * TT) + (size_t)((cn - 8) * 16 + lm) * TT + tloc) = pk;
        }
    }
}

// =====================================================================
// Kernel 3: causal flash attention + FUSED combine. R12 loop (triple-
// buffered KV, counted vmcnt). Per (b,i) group: blocks write partials,
// device-fence + atomicAdd on cnt[gid]; the LAST block acquires and
// combines the group into fp32 out. S==1 groups write out directly.
// cnt[] is zeroed by hipMemsetAsync at the top of every launch.
// =====================================================================
__global__ __launch_bounds__(256, 3) void attn(const short* __restrict__ Q,
        const short* __restrict__ K, const short* __restrict__ Vt,
        short* __restrict__ Opart, float* __restrict__ Mpart,
        float* __restrict__ Lpart, float* __restrict__ out,
        int* __restrict__ cnt) {
    __shared__ short ks[3][64 * 64];   // [buf][row=kv][d]  8KB each, swizzled
    __shared__ short vs[3][64 * 64];   // [buf][row=d][kv]  8KB each, swizzled
    __shared__ int is_last;

    const int tid  = threadIdx.x;
    const int lane = tid & 63;
    const int wv   = tid >> 6;            // 0..3
    const int lm   = lane & 15;
    const int lg   = lane >> 4;

    // ---- task decode: blockIdx.x = b*144 + t ----
    const int task = blockIdx.x;
    const int b  = task / NTASK_PB;
    int t_in = task - b * NTASK_PB;
    int g = 0;
    while (t_in >= 2 * (g + 1) * (g + 2)) ++g;          // g = i>>2, <=7
    const int idx = t_in - 2 * g * (g + 1);
    const int i   = 4 * g + idx / (g + 1);              // q-block 0..31
    const int seg = idx % (g + 1);                      // segment 0..g
    const int S   = g + 1;                              // segments for this i
    const int niter = 2 * i + 2;                        // KV-64 tiles in prefix
    const int nloop = (niter - seg + S - 1) / S;        // >= 1, block-uniform

    const size_t qkb = (size_t)b * TT * HD;
    const size_t vtb = (size_t)b * HD * TT;
    const int qrow = i * 128 + wv * 32;                 // wave's first q-row
    const int tmax = (qrow + 31) >> 6;

    bf16x8 qf0 = *reinterpret_cast<const bf16x8*>(Q + qkb + (size_t)(qrow + lm) * HD + lg * 8);
    bf16x8 qf1 = *reinterpret_cast<const bf16x8*>(Q + qkb + (size_t)(qrow + lm) * HD + 32 + lg * 8);
    bf16x8 qf2 = *reinterpret_cast<const bf16x8*>(Q + qkb + (size_t)(qrow + 16 + lm) * HD + lg * 8);
    bf16x8 qf3 = *reinterpret_cast<const bf16x8*>(Q + qkb + (size_t)(qrow + 16 + lm) * HD + 32 + lg * 8);

    f32x4 oA[4], oB[4];
    #pragma unroll
    for (int c = 0; c < 4; ++c) { oA[c] = f32x4{0.f,0.f,0.f,0.f}; oB[c] = f32x4{0.f,0.f,0.f,0.f}; }
    float mrunA = -1e30f, lrunA = 0.f;   // RAW units
    float mrunB = -1e30f, lrunB = 0.f;

    const int srcA = lm + ((lane & 16) << 1);
    const int srcB = srcA + 16;
    const bool hihalf = (lane & 32) != 0;

    int srow[2], scol[2];
    #pragma unroll
    for (int c = 0; c < 2; ++c) {
        const int off = wv * 2048 + c * 1024 + lane * 16;
        srow[c] = off >> 7;
        scol[c] = (off & 127) ^ ((srow[c] & 7) << 4);
    }

#define STAGE_KV(bufidx, tt)                                                          \
    {                                                                                 \
        _Pragma("unroll")                                                             \
        for (int c = 0; c < 2; ++c) {                                                 \
            const char* ksrc = (const char*)(K + qkb) + (tt) * 8192                   \
                               + (srow[c] << 7) + scol[c];                            \
            char* kdst = (char*)&ks[bufidx][0] + wv * 2048 + c * 1024;                \
            __builtin_amdgcn_global_load_lds(                                         \
                (const __attribute__((address_space(1))) unsigned*)ksrc,              \
                (__attribute__((address_space(3))) unsigned*)kdst, 16, 0, 0);         \
            const char* vsrc = (const char*)(Vt + vtb) + (size_t)srow[c] * (TT * 2)   \
                               + (tt) * 128 + scol[c];                                \
            char* vdst = (char*)&vs[bufidx][0] + wv * 2048 + c * 1024;                \
            __builtin_amdgcn_global_load_lds(                                         \
                (const __attribute__((address_space(1))) unsigned*)vsrc,              \
                (__attribute__((address_space(3))) unsigned*)vdst, 16, 0, 0);         \
        }                                                                             \
    }

    // ---- prologue: stage tiles 0 and 1 (if any); wait only for tile 0 ----
    STAGE_KV(0, seg)
    if (nloop > 1) {
        STAGE_KV(1, seg + S)
        asm volatile("s_waitcnt vmcnt(4)" ::: "memory");
    } else {
        asm volatile("s_waitcnt vmcnt(0)" ::: "memory");
    }
    __builtin_amdgcn_s_barrier();

    for (int n = 0; n < nloop; ++n) {
        const int t = seg + n * S;
        const bool stage2 = (n + 2 < nloop);            // block-uniform
        if (stage2) STAGE_KV((n + 2) % 3, t + 2 * S)

        if (t <= tmax) {
            const short* ksb = &ks[n % 3][0];
            const short* vsb = &vs[n % 3][0];
            const int kv = t * 64;

            // ---- QK^T swapped, both sub-tiles share k0/k1 (RAW scores) ----
            f32x4 stA[4], stB[4];
            #pragma unroll
            for (int kt = 0; kt < 4; ++kt) {
                const int krow = kt * 16 + lm;
                const int sw = (krow & 7) << 4;
                bf16x8 k0 = *reinterpret_cast<const bf16x8*>(
                    (const char*)ksb + krow * 128 + ((lg * 16) ^ sw));
                bf16x8 k1 = *reinterpret_cast<const bf16x8*>(
                    (const char*)ksb + krow * 128 + ((64 + lg * 16) ^ sw));
                f32x4 a = f32x4{0.f,0.f,0.f,0.f};
                a = __builtin_amdgcn_mfma_f32_16x16x32_bf16(k0, qf0, a, 0, 0, 0);
                a = __builtin_amdgcn_mfma_f32_16x16x32_bf16(k1, qf1, a, 0, 0, 0);
                stA[kt] = a;
                f32x4 bb2 = f32x4{0.f,0.f,0.f,0.f};
                bb2 = __builtin_amdgcn_mfma_f32_16x16x32_bf16(k0, qf2, bb2, 0, 0, 0);
                bb2 = __builtin_amdgcn_mfma_f32_16x16x32_bf16(k1, qf3, bb2, 0, 0, 0);
                stB[kt] = bb2;
            }

            // ---- causal mask on raw scores (diag tiles only) ----
            if (kv + 63 > qrow) {
                const int qgA = qrow + lm;
                const int qgB = qrow + 16 + lm;
                #pragma unroll
                for (int kt = 0; kt < 4; ++kt)
                    #pragma unroll
                    for (int r = 0; r < 4; ++r) {
                        const int kk = kv + kt * 16 + lg * 4 + r;
                        if (kk > qgA) stA[kt][r] = -1e30f;
                        if (kk > qgB) stB[kt][r] = -1e30f;
                    }
            }

            // ---- tile max (tree, then 2 shfl) ----
            float mA0 = fmaxf(fmaxf(stA[0][0], stA[0][1]), fmaxf(stA[0][2], stA[0][3]));
            float mA1 = fmaxf(fmaxf(stA[1][0], stA[1][1]), fmaxf(stA[1][2], stA[1][3]));
            float mA2 = fmaxf(fmaxf(stA[2][0], stA[2][1]), fmaxf(stA[2][2], stA[2][3]));
            float mA3 = fmaxf(fmaxf(stA[3][0], stA[3][1]), fmaxf(stA[3][2], stA[3][3]));
            float mlocA = fmaxf(fmaxf(mA0, mA1), fmaxf(mA2, mA3));
            float mB0 = fmaxf(fmaxf(stB[0][0], stB[0][1]), fmaxf(stB[0][2], stB[0][3]));
            float mB1 = fmaxf(fmaxf(stB[1][0], stB[1][1]), fmaxf(stB[1][2], stB[1][3]));
            float mB2 = fmaxf(fmaxf(stB[2][0], stB[2][1]), fmaxf(stB[2][2], stB[2][3]));
            float mB3 = fmaxf(fmaxf(stB[3][0], stB[3][1]), fmaxf(stB[3][2], stB[3][3]));
            float mlocB = fmaxf(fmaxf(mB0, mB1), fmaxf(mB2, mB3));
            mlocA = fmaxf(mlocA, __shfl_xor(mlocA, 16));
            mlocA = fmaxf(mlocA, __shfl_xor(mlocA, 32));
            mlocB = fmaxf(mlocB, __shfl_xor(mlocB, 16));
            mlocB = fmaxf(mlocB, __shfl_xor(mlocB, 32));

            // ---- defer-max: rescale only when max grew past threshold ----
            if (!__all(mlocA <= mrunA + THR_RAW)) {
                const float mnewA = fmaxf(mrunA, mlocA);
                const float alphaA = __builtin_amdgcn_exp2f((mrunA - mnewA) * C2LOG);
                mrunA = mnewA;
                lrunA *= alphaA;
                #pragma unroll
                for (int c = 0; c < 4; ++c)
                    #pragma unroll
                    for (int r = 0; r < 4; ++r) oA[c][r] *= alphaA;
            }
            if (!__all(mlocB <= mrunB + THR_RAW)) {
                const float mnewB = fmaxf(mrunB, mlocB);
                const float alphaB = __builtin_amdgcn_exp2f((mrunB - mnewB) * C2LOG);
                mrunB = mnewB;
                lrunB *= alphaB;
                #pragma unroll
                for (int c = 0; c < 4; ++c)
                    #pragma unroll
                    for (int r = 0; r < 4; ++r) oB[c][r] *= alphaB;
            }

            // ---- p = exp2(fma(st, C2LOG, -m*C2LOG)) ----
            const float ncA = -mrunA * C2LOG;
            const float ncB = -mrunB * C2LOG;
            float pA[4][4], pB[4][4];
            float rsA = 0.f, rsB = 0.f;
            #pragma unroll
            for (int kt = 0; kt < 4; ++kt)
                #pragma unroll
                for (int r = 0; r < 4; ++r) {
                    pA[kt][r] = __builtin_amdgcn_exp2f(__builtin_fmaf(stA[kt][r], C2LOG, ncA));
                    rsA += pA[kt][r];
                    pB[kt][r] = __builtin_amdgcn_exp2f(__builtin_fmaf(stB[kt][r], C2LOG, ncB));
                    rsB += pB[kt][r];
                }
            rsA += __shfl_xor(rsA, 16); rsA += __shfl_xor(rsA, 32);
            rsB += __shfl_xor(rsB, 16); rsB += __shfl_xor(rsB, 32);
            lrunA += rsA;
            lrunB += rsB;

            // ---- pack P^T to bf16 pairs (HW cvt_pk) ----
            unsigned uA[4][2], uB[4][2];
            #pragma unroll
            for (int kt = 0; kt < 4; ++kt) {
                uA[kt][0] = cvtpk(pA[kt][0], pA[kt][1]);
                uA[kt][1] = cvtpk(pA[kt][2], pA[kt][3]);
                uB[kt][0] = cvtpk(pB[kt][0], pB[kt][1]);
                uB[kt][1] = cvtpk(pB[kt][2], pB[kt][3]);
            }

            // ---- PV: both sub-tiles share va reads ----
            #pragma unroll
            for (int h = 0; h < 2; ++h) {
                const int a0 = __shfl((int)uA[2*h][0],   srcA);
                const int a1c = __shfl((int)uA[2*h+1][0], srcA);
                const int a2 = __shfl((int)uA[2*h][1],   srcA);
                const int a3c = __shfl((int)uA[2*h+1][1], srcA);
                const int a4 = __shfl((int)uA[2*h][0],   srcB);
                const int a5c = __shfl((int)uA[2*h+1][0], srcB);
                const int a6 = __shfl((int)uA[2*h][1],   srcB);
                const int a7c = __shfl((int)uA[2*h+1][1], srcB);
                union { i32x4 iv; bf16x8 v; } cvA;
                cvA.iv = i32x4{ hihalf ? a1c : a0, hihalf ? a3c : a2,
                                hihalf ? a5c : a4, hihalf ? a7c : a6 };
                const int b0 = __shfl((int)uB[2*h][0],   srcA);
                const int b1c = __shfl((int)uB[2*h+1][0], srcA);
                const int b2 = __shfl((int)uB[2*h][1],   srcA);
                const int b3c = __shfl((int)uB[2*h+1][1], srcA);
                const int b4 = __shfl((int)uB[2*h][0],   srcB);
                const int b5c = __shfl((int)uB[2*h+1][0], srcB);
                const int b6 = __shfl((int)uB[2*h][1],   srcB);
                const int b7c = __shfl((int)uB[2*h+1][1], srcB);
                union { i32x4 iv; bf16x8 v; } cvB;
                cvB.iv = i32x4{ hihalf ? b1c : b0, hihalf ? b3c : b2,
                                hihalf ? b5c : b4, hihalf ? b7c : b6 };
                #pragma unroll
                for (int c = 0; c < 4; ++c) {
                    const int vrow = c * 16 + lm;
                    const int sw = (vrow & 7) << 4;
                    bf16x8 va = *reinterpret_cast<const bf16x8*>(
                        (const char*)vsb + vrow * 128 + ((h * 64 + lg * 16) ^ sw));
                    oA[c] = __builtin_amdgcn_mfma_f32_16x16x32_bf16(va, cvA.v, oA[c], 0, 0, 0);
                    oB[c] = __builtin_amdgcn_mfma_f32_16x16x32_bf16(va, cvB.v, oB[c], 0, 0, 0);
                }
            }
        }

        // ---- counted drain: wait only for next-needed buffer's stage ----
        __builtin_amdgcn_sched_barrier(0);
        asm volatile("s_waitcnt lgkmcnt(0)" ::: "memory");
        if (stage2) asm volatile("s_waitcnt vmcnt(4)" ::: "memory");
        else        asm volatile("s_waitcnt vmcnt(0)" ::: "memory");
        __builtin_amdgcn_s_barrier();
    }
#undef STAGE_KV

    // ================= epilogue: partials + fused combine =================
    if (S == 1) {
        // single-segment group: write normalized output directly
        const float invA = 1.0f / lrunA;
        const float invB = 1.0f / lrunB;
        float* Orow = out + ((size_t)b * TT + i * 128) * HD;
        #pragma unroll
        for (int c = 0; c < 4; ++c) {
            f32x4 ra, rb;
            #pragma unroll
            for (int r = 0; r < 4; ++r) { ra[r] = oA[c][r] * invA; rb[r] = oB[c][r] * invB; }
            *reinterpret_cast<f32x4*>(&Orow[(size_t)(wv * 32 + lm) * HD + c * 16 + lg * 4]) = ra;
            *reinterpret_cast<f32x4*>(&Orow[(size_t)(wv * 32 + 16 + lm) * HD + c * 16 + lg * 4]) = rb;
        }
        return;
    }

    // ---- write partials: O bf16 (task,row,d), m (RAW)/l fp32 ----
    short* Ob = Opart + (size_t)task * (128 * HD);
    #pragma unroll
    for (int c = 0; c < 4; ++c) {
        int2 pkA, pkB;
        pkA.x = (int)cvtpk(oA[c][0], oA[c][1]);
        pkA.y = (int)cvtpk(oA[c][2], oA[c][3]);
        pkB.x = (int)cvtpk(oB[c][0], oB[c][1]);
        pkB.y = (int)cvtpk(oB[c][2], oB[c][3]);
        *reinterpret_cast<int2*>(&Ob[(wv * 32 + lm) * HD + c * 16 + lg * 4]) = pkA;
        *reinterpret_cast<int2*>(&Ob[(wv * 32 + 16 + lm) * HD + c * 16 + lg * 4]) = pkB;
    }
    if (lg == 0) {
        Mpart[task * 128 + wv * 32 + lm] = mrunA;
        Lpart[task * 128 + wv * 32 + lm] = lrunA;
        Mpart[task * 128 + wv * 32 + 16 + lm] = mrunB;
        Lpart[task * 128 + wv * 32 + 16 + lm] = lrunB;
    }

    // ---- release partials, count arrivals; last block combines ----
    __threadfence();
    if (tid == 0) {
        const int gid = (b << 5) + i;
        is_last = (atomicAdd(&cnt[gid], 1) == S - 1);
    }
    __syncthreads();
    if (!is_last) return;
    __threadfence();   // acquire: see all blocks' partials

    const int task0 = task - seg;          // group's tasks are contiguous
    const int row0  = tid >> 4;            // 0..15
    const int cb    = (tid & 15) << 2;     // col (x4 floats)
    for (int rr = 0; rr < 8; ++rr) {
        const int row = rr * 16 + row0;    // 0..127
        float mmax = -1e30f;
        float ms[8];
        for (int s = 0; s < S; ++s) {
            ms[s] = Mpart[(task0 + s) * 128 + row];
            mmax = fmaxf(mmax, ms[s]);
        }
        float lsum = 0.f;
        float a0 = 0.f, a1 = 0.f, a2 = 0.f, a3 = 0.f;
        for (int s = 0; s < S; ++s) {
            const float w = __builtin_amdgcn_exp2f((ms[s] - mmax) * C2LOG);
            lsum += Lpart[(task0 + s) * 128 + row] * w;
            bf16x4 ov = *reinterpret_cast<const bf16x4*>(
                &Opart[((size_t)(task0 + s) * 128 + row) * HD + cb]);
            a0 += bf2f(ov[0]) * w;
            a1 += bf2f(ov[1]) * w;
            a2 += bf2f(ov[2]) * w;
            a3 += bf2f(ov[3]) * w;
        }
        const float inv = 1.0f / lsum;
        f32x4 res{ a0 * inv, a1 * inv, a2 * inv, a3 * inv };
        *reinterpret_cast<f32x4*>(
            &out[((size_t)b * TT + i * 128 + row) * HD + cb]) = res;
    }
}

// =====================================================================
extern "C" void kernel_launch(void* const* d_in, const int* in_sizes, int n_in,
                              void* d_out, int out_size, void* d_ws, size_t ws_size,
                              hipStream_t stream) {
    const float* x  = (const float*)d_in[0];
    const float* Wq = (const float*)d_in[1];
    const float* Wk = (const float*)d_in[2];
    const float* Wv = (const float*)d_in[3];
    float* out = (float*)d_out;

    char* ws = (char*)d_ws;
    short* Wt    = (short*)(ws);                          // 393216 B
    short* Q     = (short*)(ws + 393216);                 // 2097152 B
    short* K     = (short*)(ws + 2490368);                // 2097152 B
    short* Vt    = (short*)(ws + 4587520);                // 2097152 B
    short* Opart = (short*)(ws + 6684672);                // 576*128*64*2 = 9437184 B
    float* Mpart = (float*)(ws + 16121856);               // 294912 B
    float* Lpart = (float*)(ws + 16416768);               // 294912 B
    int*   cnt   = (int*)(ws + 16711680);                 // 128*4 = 512 B
    // total: ~16.7 MiB (ws is ~268 MB per harness poison fills)

    hipMemsetAsync(cnt, 0, 128 * sizeof(int), stream);    // reset group counters
    hipLaunchKernelGGL(prep_w,   dim3(48),    dim3(256), 0, stream, Wq, Wk, Wv, Wt);
    hipLaunchKernelGGL(proj_qkv, dim3(512),   dim3(512), 0, stream, x, Wt, Q, K, Vt);
    hipLaunchKernelGGL(attn,     dim3(NTASK), dim3(256), 0, stream, Q, K, Vt,
                       Opart, Mpart, Lpart, out, cnt);
}

// Round 14
// 65.849 us; speedup vs baseline: 2.8123x; 2.8123x over previous
//
#include <hip/hip_runtime.h>
#include <hip/hip_bf16.h>

// ---------- types ----------
typedef __attribute__((ext_vector_type(8))) short bf16x8;   // 8 bf16 in 4 VGPRs
typedef __attribute__((ext_vector_type(4))) short bf16x4;   // 4 bf16 in 2 VGPRs
typedef __attribute__((ext_vector_type(4))) float f32x4;
typedef __attribute__((ext_vector_type(4))) int   i32x4;

#define C2LOG 0.18033688011112042f   // 0.125 * log2(e): folds 1/sqrt(64) + base-2
#define THR_RAW 44.3616f             // 8 / C2LOG : defer-max threshold (raw units)

// fp32 -> bf16 round-to-nearest-even (scalar)
__device__ __forceinline__ short f2bf(float f) {
    union { float f; unsigned u; } v; v.f = f;
    unsigned r = v.u + 0x7fff + ((v.u >> 16) & 1);
    return (short)(r >> 16);
}
// HW packed conversion: 2 fp32 -> u32 of 2 bf16 (RNE), one instruction
__device__ __forceinline__ unsigned cvtpk(float lo, float hi) {
    unsigned r;
    asm("v_cvt_pk_bf16_f32 %0, %1, %2" : "=v"(r) : "v"(lo), "v"(hi));
    return r;
}
__device__ __forceinline__ float bf2f(short s) {
    union { unsigned u; float f; } v; v.u = ((unsigned)(unsigned short)s) << 16;
    return v.f;
}

// ---------- sizes ----------
#define BB 4
#define TT 4096
#define CC 1024
#define HD 64
#define NTASK_PB 144          // tasks per batch: sum_{g=0}^{7} 4*(g+1) = 144  (R9 split)
#define NTASK (BB * NTASK_PB) // 576

// =====================================================================
// Kernel 1: pack W q/k/v -> transposed bf16 Wt[192][1024], COALESCED
// (LDS transpose, pad 65).
// =====================================================================
__global__ __launch_bounds__(256) void prep_w(const float* __restrict__ Wq,
        const float* __restrict__ Wk, const float* __restrict__ Wv,
        short* __restrict__ Wt) {
    __shared__ float wls[64][65];
    const int w = blockIdx.x >> 4;            // 0..2
    const int c = blockIdx.x & 15;            // k-chunk
    const float* W = (w == 0) ? Wq : (w == 1) ? Wk : Wv;

    const int r  = threadIdx.x >> 4;          // 0..15
    const int q4 = threadIdx.x & 15;          // float4 col
    #pragma unroll
    for (int rr = 0; rr < 4; ++rr) {
        const int row = rr * 16 + r;          // 0..63 (k-local)
        float4 v = *reinterpret_cast<const float4*>(
            W + (size_t)(c * 64 + row) * HD + q4 * 4);
        wls[row][q4 * 4 + 0] = v.x;
        wls[row][q4 * 4 + 1] = v.y;
        wls[row][q4 * 4 + 2] = v.z;
        wls[row][q4 * 4 + 3] = v.w;
    }
    __syncthreads();

    const int n  = threadIdx.x >> 2;          // 0..63 (output row within W)
    const int ks = (threadIdx.x & 3) * 16;    // k-offset within chunk
    bf16x8 o0, o1;
    #pragma unroll
    for (int j = 0; j < 8; ++j) o0[j] = f2bf(wls[ks + j][n]);
    #pragma unroll
    for (int j = 0; j < 8; ++j) o1[j] = f2bf(wls[ks + 8 + j][n]);
    short* dst = Wt + (size_t)(w * 64 + n) * CC + c * 64 + ks;
    *reinterpret_cast<bf16x8*>(dst)     = o0;
    *reinterpret_cast<bf16x8*>(dst + 8) = o1;
}

// =====================================================================
// Kernel 2: QKV projection (R9 proven version: xs LDS staging + W DMA
// double-buffer, one vmcnt(0)+barrier per K-chunk).
// =====================================================================
__global__ __launch_bounds__(512) void proj_qkv(const float* __restrict__ x,
        const short* __restrict__ Wt, short* __restrict__ Q,
        short* __restrict__ K, short* __restrict__ Vt) {
    __shared__ short xs[2][32 * 72];      // x tile bf16, pad-72 (reg-staged)
    __shared__ short wsm[2][192 * 64];    // W chunk bf16, 128B rows, XOR-swizzled

    const int tid  = threadIdx.x;
    const int lane = tid & 63;
    const int wv   = tid >> 6;
    const int lm   = lane & 15;
    const int lg   = lane >> 4;
    const int mhalf = wv & 1;
    const int ngrp  = wv >> 1;
    const int mbase = blockIdx.x * 32;

    const int xr  = tid >> 4;             // 0..31
    const int xq4 = tid & 15;             // float4 index within chunk
    const float* xrow = x + (size_t)(mbase + xr) * CC;

    int wsrow[3], wscol[3];
    #pragma unroll
    for (int it = 0; it < 3; ++it) {
        const int off = it * 8192 + wv * 1024 + lane * 16;
        wsrow[it] = off >> 7;
        wscol[it] = (off & 127) ^ ((wsrow[it] & 7) << 4);
    }

#define STAGE_W(bufidx, kc)                                                           \
    {                                                                                 \
        _Pragma("unroll")                                                             \
        for (int it = 0; it < 3; ++it) {                                              \
            const char* src = (const char*)(Wt + (size_t)wsrow[it] * CC + (kc) * 64)  \
                              + wscol[it];                                            \
            char* dst = (char*)&wsm[bufidx][0] + it * 8192 + wv * 1024;               \
            __builtin_amdgcn_global_load_lds(                                         \
                (const __attribute__((address_space(1))) unsigned*)src,               \
                (__attribute__((address_space(3))) unsigned*)dst, 16, 0, 0);          \
        }                                                                             \
    }

#define CONV_X(bufidx, xv)                                                            \
    {                                                                                 \
        int2 pk;                                                                      \
        pk.x = (int)cvtpk((xv).x, (xv).y);                                            \
        pk.y = (int)cvtpk((xv).z, (xv).w);                                            \
        *reinterpret_cast<int2*>(&xs[bufidx][xr * 72 + xq4 * 4]) = pk;                \
    }

    f32x4 acc[3];
    #pragma unroll
    for (int i = 0; i < 3; ++i) acc[i] = f32x4{0.f, 0.f, 0.f, 0.f};

    {
        float4 v = *reinterpret_cast<const float4*>(xrow + xq4 * 4);
        CONV_X(0, v)
        STAGE_W(0, 0)
    }
    asm volatile("s_waitcnt vmcnt(0)" ::: "memory");
    __syncthreads();

    const int arow = mhalf * 16 + lm;
    int buf = 0;
    for (int kc = 0; kc < 16; ++kc) {
        float4 nv;
        const bool more = (kc < 15);
        if (more) {
            nv = *reinterpret_cast<const float4*>(xrow + (kc + 1) * 64 + xq4 * 4);
            STAGE_W(buf ^ 1, kc + 1)
        }

        bf16x8 a0 = *reinterpret_cast<const bf16x8*>(&xs[buf][arow * 72 + lg * 8]);
        bf16x8 a1 = *reinterpret_cast<const bf16x8*>(&xs[buf][arow * 72 + 32 + lg * 8]);
        #pragma unroll
        for (int c = 0; c < 3; ++c) {
            const int brow = (ngrp * 3 + c) * 16 + lm;
            const int sw = (brow & 7) << 4;
            bf16x8 b0 = *reinterpret_cast<const bf16x8*>(
                (const char*)&wsm[buf][0] + brow * 128 + ((lg * 16) ^ sw));
            bf16x8 b1 = *reinterpret_cast<const bf16x8*>(
                (const char*)&wsm[buf][0] + brow * 128 + ((64 + lg * 16) ^ sw));
            acc[c] = __builtin_amdgcn_mfma_f32_16x16x32_bf16(a0, b0, acc[c], 0, 0, 0);
            acc[c] = __builtin_amdgcn_mfma_f32_16x16x32_bf16(a1, b1, acc[c], 0, 0, 0);
        }

        if (more) CONV_X(buf ^ 1, nv)
        asm volatile("s_waitcnt vmcnt(0)" ::: "memory");
        __syncthreads();
        buf ^= 1;
    }
#undef STAGE_W
#undef CONV_X

    const int mrow = mbase + mhalf * 16 + lg * 4;
    #pragma unroll
    for (int c = 0; c < 3; ++c) {
        const int cn = ngrp * 3 + c;
        if (cn < 4) {
            #pragma unroll
            for (int r = 0; r < 4; ++r)
                Q[(size_t)(mrow + r) * HD + cn * 16 + lm] = f2bf(acc[c][r]);
        } else if (cn < 8) {
            #pragma unroll
            for (int r = 0; r < 4; ++r)
                K[(size_t)(mrow + r) * HD + (cn - 4) * 16 + lm] = f2bf(acc[c][r]);
        } else {
            const int bb   = mbase >> 12;
            const int tloc = (mbase & 4095) + mhalf * 16 + lg * 4;
            int2 pk;
            pk.x = (int)cvtpk(acc[c][0], acc[c][1]);
            pk.y = (int)cvtpk(acc[c][2], acc[c][3]);
            *reinterpret_cast<int2*>(
                Vt + (size_t)bb * (HD * TT) + (size_t)((cn - 8) * 16 + lm) * TT + tloc) = pk;
        }
    }
}

// =====================================================================
// Kernel 3: causal flash attention (R12 loop: triple-buffered KV,
// counted vmcnt, raw s_barrier) + XCD-CHUNKED task remap: blocks on one
// XCD get a contiguous task range (same-batch tasks share the KV prefix
// -> ~1 MB working set per XCD L2 instead of ~4 MB). 576 % 8 == 0 so
// the remap (bid&7)*72 + (bid>>3) is bijective.
// =====================================================================
__global__ __launch_bounds__(256, 3) void attn(const short* __restrict__ Q,
        const short* __restrict__ K, const short* __restrict__ Vt,
        short* __restrict__ Opart, float* __restrict__ Mpart,
        float* __restrict__ Lpart) {
    __shared__ short ks[3][64 * 64];   // [buf][row=kv][d]  8KB each, swizzled
    __shared__ short vs[3][64 * 64];   // [buf][row=d][kv]  8KB each, swizzled

    const int tid  = threadIdx.x;
    const int lane = tid & 63;
    const int wv   = tid >> 6;            // 0..3
    const int lm   = lane & 15;
    const int lg   = lane >> 4;

    // ---- XCD-chunked remap, then task decode: task = b*144 + t ----
    const int task = (blockIdx.x & 7) * (NTASK / 8) + (blockIdx.x >> 3);
    const int b  = task / NTASK_PB;
    int t_in = task - b * NTASK_PB;
    int g = 0;
    while (t_in >= 2 * (g + 1) * (g + 2)) ++g;          // g = i>>2, <=7
    const int idx = t_in - 2 * g * (g + 1);
    const int i   = 4 * g + idx / (g + 1);              // q-block 0..31
    const int seg = idx % (g + 1);                      // segment 0..g
    const int S   = g + 1;                              // segments for this i
    const int niter = 2 * i + 2;                        // KV-64 tiles in prefix
    const int nloop = (niter - seg + S - 1) / S;        // >= 1, block-uniform

    const size_t qkb = (size_t)b * TT * HD;
    const size_t vtb = (size_t)b * HD * TT;
    const int qrow = i * 128 + wv * 32;                 // wave's first q-row
    const int tmax = (qrow + 31) >> 6;

    bf16x8 qf0 = *reinterpret_cast<const bf16x8*>(Q + qkb + (size_t)(qrow + lm) * HD + lg * 8);
    bf16x8 qf1 = *reinterpret_cast<const bf16x8*>(Q + qkb + (size_t)(qrow + lm) * HD + 32 + lg * 8);
    bf16x8 qf2 = *reinterpret_cast<const bf16x8*>(Q + qkb + (size_t)(qrow + 16 + lm) * HD + lg * 8);
    bf16x8 qf3 = *reinterpret_cast<const bf16x8*>(Q + qkb + (size_t)(qrow + 16 + lm) * HD + 32 + lg * 8);

    f32x4 oA[4], oB[4];
    #pragma unroll
    for (int c = 0; c < 4; ++c) { oA[c] = f32x4{0.f,0.f,0.f,0.f}; oB[c] = f32x4{0.f,0.f,0.f,0.f}; }
    float mrunA = -1e30f, lrunA = 0.f;   // RAW units
    float mrunB = -1e30f, lrunB = 0.f;

    const int srcA = lm + ((lane & 16) << 1);
    const int srcB = srcA + 16;
    const bool hihalf = (lane & 32) != 0;

    int srow[2], scol[2];
    #pragma unroll
    for (int c = 0; c < 2; ++c) {
        const int off = wv * 2048 + c * 1024 + lane * 16;
        srow[c] = off >> 7;
        scol[c] = (off & 127) ^ ((srow[c] & 7) << 4);
    }

#define STAGE_KV(bufidx, tt)                                                          \
    {                                                                                 \
        _Pragma("unroll")                                                             \
        for (int c = 0; c < 2; ++c) {                                                 \
            const char* ksrc = (const char*)(K + qkb) + (tt) * 8192                   \
                               + (srow[c] << 7) + scol[c];                            \
            char* kdst = (char*)&ks[bufidx][0] + wv * 2048 + c * 1024;                \
            __builtin_amdgcn_global_load_lds(                                         \
                (const __attribute__((address_space(1))) unsigned*)ksrc,              \
                (__attribute__((address_space(3))) unsigned*)kdst, 16, 0, 0);         \
            const char* vsrc = (const char*)(Vt + vtb) + (size_t)srow[c] * (TT * 2)   \
                               + (tt) * 128 + scol[c];                                \
            char* vdst = (char*)&vs[bufidx][0] + wv * 2048 + c * 1024;                \
            __builtin_amdgcn_global_load_lds(                                         \
                (const __attribute__((address_space(1))) unsigned*)vsrc,              \
                (__attribute__((address_space(3))) unsigned*)vdst, 16, 0, 0);         \
        }                                                                             \
    }

    // ---- prologue: stage tiles 0 and 1 (if any); wait only for tile 0 ----
    STAGE_KV(0, seg)
    if (nloop > 1) {
        STAGE_KV(1, seg + S)
        asm volatile("s_waitcnt vmcnt(4)" ::: "memory");
    } else {
        asm volatile("s_waitcnt vmcnt(0)" ::: "memory");
    }
    __builtin_amdgcn_s_barrier();

    for (int n = 0; n < nloop; ++n) {
        const int t = seg + n * S;
        const bool stage2 = (n + 2 < nloop);            // block-uniform
        if (stage2) STAGE_KV((n + 2) % 3, t + 2 * S)

        if (t <= tmax) {
            const short* ksb = &ks[n % 3][0];
            const short* vsb = &vs[n % 3][0];
            const int kv = t * 64;

            // ---- QK^T swapped, both sub-tiles share k0/k1 (RAW scores) ----
            f32x4 stA[4], stB[4];
            #pragma unroll
            for (int kt = 0; kt < 4; ++kt) {
                const int krow = kt * 16 + lm;
                const int sw = (krow & 7) << 4;
                bf16x8 k0 = *reinterpret_cast<const bf16x8*>(
                    (const char*)ksb + krow * 128 + ((lg * 16) ^ sw));
                bf16x8 k1 = *reinterpret_cast<const bf16x8*>(
                    (const char*)ksb + krow * 128 + ((64 + lg * 16) ^ sw));
                f32x4 a = f32x4{0.f,0.f,0.f,0.f};
                a = __builtin_amdgcn_mfma_f32_16x16x32_bf16(k0, qf0, a, 0, 0, 0);
                a = __builtin_amdgcn_mfma_f32_16x16x32_bf16(k1, qf1, a, 0, 0, 0);
                stA[kt] = a;
                f32x4 bb2 = f32x4{0.f,0.f,0.f,0.f};
                bb2 = __builtin_amdgcn_mfma_f32_16x16x32_bf16(k0, qf2, bb2, 0, 0, 0);
                bb2 = __builtin_amdgcn_mfma_f32_16x16x32_bf16(k1, qf3, bb2, 0, 0, 0);
                stB[kt] = bb2;
            }

            // ---- causal mask on raw scores (diag tiles only) ----
            if (kv + 63 > qrow) {
                const int qgA = qrow + lm;
                const int qgB = qrow + 16 + lm;
                #pragma unroll
                for (int kt = 0; kt < 4; ++kt)
                    #pragma unroll
                    for (int r = 0; r < 4; ++r) {
                        const int kk = kv + kt * 16 + lg * 4 + r;
                        if (kk > qgA) stA[kt][r] = -1e30f;
                        if (kk > qgB) stB[kt][r] = -1e30f;
                    }
            }

            // ---- tile max (tree, then 2 shfl) ----
            float mA0 = fmaxf(fmaxf(stA[0][0], stA[0][1]), fmaxf(stA[0][2], stA[0][3]));
            float mA1 = fmaxf(fmaxf(stA[1][0], stA[1][1]), fmaxf(stA[1][2], stA[1][3]));
            float mA2 = fmaxf(fmaxf(stA[2][0], stA[2][1]), fmaxf(stA[2][2], stA[2][3]));
            float mA3 = fmaxf(fmaxf(stA[3][0], stA[3][1]), fmaxf(stA[3][2], stA[3][3]));
            float mlocA = fmaxf(fmaxf(mA0, mA1), fmaxf(mA2, mA3));
            float mB0 = fmaxf(fmaxf(stB[0][0], stB[0][1]), fmaxf(stB[0][2], stB[0][3]));
            float mB1 = fmaxf(fmaxf(stB[1][0], stB[1][1]), fmaxf(stB[1][2], stB[1][3]));
            float mB2 = fmaxf(fmaxf(stB[2][0], stB[2][1]), fmaxf(stB[2][2], stB[2][3]));
            float mB3 = fmaxf(fmaxf(stB[3][0], stB[3][1]), fmaxf(stB[3][2], stB[3][3]));
            float mlocB = fmaxf(fmaxf(mB0, mB1), fmaxf(mB2, mB3));
            mlocA = fmaxf(mlocA, __shfl_xor(mlocA, 16));
            mlocA = fmaxf(mlocA, __shfl_xor(mlocA, 32));
            mlocB = fmaxf(mlocB, __shfl_xor(mlocB, 16));
            mlocB = fmaxf(mlocB, __shfl_xor(mlocB, 32));

            // ---- defer-max: rescale only when max grew past threshold ----
            if (!__all(mlocA <= mrunA + THR_RAW)) {
                const float mnewA = fmaxf(mrunA, mlocA);
                const float alphaA = __builtin_amdgcn_exp2f((mrunA - mnewA) * C2LOG);
                mrunA = mnewA;
                lrunA *= alphaA;
                #pragma unroll
                for (int c = 0; c < 4; ++c)
                    #pragma unroll
                    for (int r = 0; r < 4; ++r) oA[c][r] *= alphaA;
            }
            if (!__all(mlocB <= mrunB + THR_RAW)) {
                const float mnewB = fmaxf(mrunB, mlocB);
                const float alphaB = __builtin_amdgcn_exp2f((mrunB - mnewB) * C2LOG);
                mrunB = mnewB;
                lrunB *= alphaB;
                #pragma unroll
                for (int c = 0; c < 4; ++c)
                    #pragma unroll
                    for (int r = 0; r < 4; ++r) oB[c][r] *= alphaB;
            }

            // ---- p = exp2(fma(st, C2LOG, -m*C2LOG)) ----
            const float ncA = -mrunA * C2LOG;
            const float ncB = -mrunB * C2LOG;
            float pA[4][4], pB[4][4];
            float rsA = 0.f, rsB = 0.f;
            #pragma unroll
            for (int kt = 0; kt < 4; ++kt)
                #pragma unroll
                for (int r = 0; r < 4; ++r) {
                    pA[kt][r] = __builtin_amdgcn_exp2f(__builtin_fmaf(stA[kt][r], C2LOG, ncA));
                    rsA += pA[kt][r];
                    pB[kt][r] = __builtin_amdgcn_exp2f(__builtin_fmaf(stB[kt][r], C2LOG, ncB));
                    rsB += pB[kt][r];
                }
            rsA += __shfl_xor(rsA, 16); rsA += __shfl_xor(rsA, 32);
            rsB += __shfl_xor(rsB, 16); rsB += __shfl_xor(rsB, 32);
            lrunA += rsA;
            lrunB += rsB;

            // ---- pack P^T to bf16 pairs (HW cvt_pk) ----
            unsigned uA[4][2], uB[4][2];
            #pragma unroll
            for (int kt = 0; kt < 4; ++kt) {
                uA[kt][0] = cvtpk(pA[kt][0], pA[kt][1]);
                uA[kt][1] = cvtpk(pA[kt][2], pA[kt][3]);
                uB[kt][0] = cvtpk(pB[kt][0], pB[kt][1]);
                uB[kt][1] = cvtpk(pB[kt][2], pB[kt][3]);
            }

            // ---- PV: both sub-tiles share va reads ----
            #pragma unroll
            for (int h = 0; h < 2; ++h) {
                const int a0 = __shfl((int)uA[2*h][0],   srcA);
                const int a1c = __shfl((int)uA[2*h+1][0], srcA);
                const int a2 = __shfl((int)uA[2*h][1],   srcA);
                const int a3c = __shfl((int)uA[2*h+1][1], srcA);
                const int a4 = __shfl((int)uA[2*h][0],   srcB);
                const int a5c = __shfl((int)uA[2*h+1][0], srcB);
                const int a6 = __shfl((int)uA[2*h][1],   srcB);
                const int a7c = __shfl((int)uA[2*h+1][1], srcB);
                union { i32x4 iv; bf16x8 v; } cvA;
                cvA.iv = i32x4{ hihalf ? a1c : a0, hihalf ? a3c : a2,
                                hihalf ? a5c : a4, hihalf ? a7c : a6 };
                const int b0 = __shfl((int)uB[2*h][0],   srcA);
                const int b1c = __shfl((int)uB[2*h+1][0], srcA);
                const int b2 = __shfl((int)uB[2*h][1],   srcA);
                const int b3c = __shfl((int)uB[2*h+1][1], srcA);
                const int b4 = __shfl((int)uB[2*h][0],   srcB);
                const int b5c = __shfl((int)uB[2*h+1][0], srcB);
                const int b6 = __shfl((int)uB[2*h][1],   srcB);
                const int b7c = __shfl((int)uB[2*h+1][1], srcB);
                union { i32x4 iv; bf16x8 v; } cvB;
                cvB.iv = i32x4{ hihalf ? b1c : b0, hihalf ? b3c : b2,
                                hihalf ? b5c : b4, hihalf ? b7c : b6 };
                #pragma unroll
                for (int c = 0; c < 4; ++c) {
                    const int vrow = c * 16 + lm;
                    const int sw = (vrow & 7) << 4;
                    bf16x8 va = *reinterpret_cast<const bf16x8*>(
                        (const char*)vsb + vrow * 128 + ((h * 64 + lg * 16) ^ sw));
                    oA[c] = __builtin_amdgcn_mfma_f32_16x16x32_bf16(va, cvA.v, oA[c], 0, 0, 0);
                    oB[c] = __builtin_amdgcn_mfma_f32_16x16x32_bf16(va, cvB.v, oB[c], 0, 0, 0);
                }
            }
        }

        // ---- counted drain: wait only for next-needed buffer's stage ----
        __builtin_amdgcn_sched_barrier(0);
        asm volatile("s_waitcnt lgkmcnt(0)" ::: "memory");
        if (stage2) asm volatile("s_waitcnt vmcnt(4)" ::: "memory");
        else        asm volatile("s_waitcnt vmcnt(0)" ::: "memory");
        __builtin_amdgcn_s_barrier();
    }
#undef STAGE_KV

    // ---- write partials: O bf16 (task,row,d), m (RAW)/l fp32 ----
    short* Ob = Opart + (size_t)task * (128 * HD);
    #pragma unroll
    for (int c = 0; c < 4; ++c) {
        int2 pkA, pkB;
        pkA.x = (int)cvtpk(oA[c][0], oA[c][1]);
        pkA.y = (int)cvtpk(oA[c][2], oA[c][3]);
        pkB.x = (int)cvtpk(oB[c][0], oB[c][1]);
        pkB.y = (int)cvtpk(oB[c][2], oB[c][3]);
        *reinterpret_cast<int2*>(&Ob[(wv * 32 + lm) * HD + c * 16 + lg * 4]) = pkA;
        *reinterpret_cast<int2*>(&Ob[(wv * 32 + 16 + lm) * HD + c * 16 + lg * 4]) = pkB;
    }
    if (lg == 0) {
        Mpart[task * 128 + wv * 32 + lm] = mrunA;
        Lpart[task * 128 + wv * 32 + lm] = lrunA;
        Mpart[task * 128 + wv * 32 + 16 + lm] = mrunB;
        Lpart[task * 128 + wv * 32 + 16 + lm] = lrunB;
    }
}

// =====================================================================
// Kernel 4: combine partials -> fp32 out (R9 version; Mpart RAW units).
// =====================================================================
__global__ __launch_bounds__(256) void combine(const short* __restrict__ Opart,
        const float* __restrict__ Mpart, const float* __restrict__ Lpart,
        float* __restrict__ out) {
    const int b   = blockIdx.x >> 8;
    const int rem = blockIdx.x & 255;
    const int i   = rem >> 3;
    const int rr  = rem & 7;
    const int g = i >> 2;
    const int S = g + 1;
    const int task0 = b * NTASK_PB + 2 * g * (g + 1) + (i - 4 * g) * (g + 1);
    const int qbase = i * 128;

    const int tid = threadIdx.x;
    const int row = rr * 16 + (tid >> 4);   // 0..127
    const int cb  = (tid & 15) << 2;        // col (x4 floats)

    float mmax = -1e30f;
    float ms[8];
    for (int s = 0; s < S; ++s) {
        ms[s] = Mpart[(task0 + s) * 128 + row];
        mmax = fmaxf(mmax, ms[s]);
    }
    float lsum = 0.f;
    float a0 = 0.f, a1 = 0.f, a2 = 0.f, a3 = 0.f;
    for (int s = 0; s < S; ++s) {
        const float w = __builtin_amdgcn_exp2f((ms[s] - mmax) * C2LOG);
        lsum += Lpart[(task0 + s) * 128 + row] * w;
        bf16x4 ov = *reinterpret_cast<const bf16x4*>(
            &Opart[((size_t)(task0 + s) * 128 + row) * HD + cb]);
        a0 += bf2f(ov[0]) * w;
        a1 += bf2f(ov[1]) * w;
        a2 += bf2f(ov[2]) * w;
        a3 += bf2f(ov[3]) * w;
    }
    const float inv = 1.0f / lsum;
    f32x4 res{ a0 * inv, a1 * inv, a2 * inv, a3 * inv };
    *reinterpret_cast<f32x4*>(
        &out[((size_t)b * TT + qbase + row) * HD + cb]) = res;
}

// =====================================================================
extern "C" void kernel_launch(void* const* d_in, const int* in_sizes, int n_in,
                              void* d_out, int out_size, void* d_ws, size_t ws_size,
                              hipStream_t stream) {
    const float* x  = (const float*)d_in[0];
    const float* Wq = (const float*)d_in[1];
    const float* Wk = (const float*)d_in[2];
    const float* Wv = (const float*)d_in[3];
    float* out = (float*)d_out;

    char* ws = (char*)d_ws;
    short* Wt    = (short*)(ws);                          // 393216 B
    short* Q     = (short*)(ws + 393216);                 // 2097152 B
    short* K     = (short*)(ws + 2490368);                // 2097152 B
    short* Vt    = (short*)(ws + 4587520);                // 2097152 B
    short* Opart = (short*)(ws + 6684672);                // 576*128*64*2 = 9437184 B
    float* Mpart = (float*)(ws + 16121856);               // 294912 B
    float* Lpart = (float*)(ws + 16416768);               // 294912 B
    // total: ~16.7 MiB (ws is ~268 MB per harness poison fills)

    hipLaunchKernelGGL(prep_w,   dim3(48),    dim3(256), 0, stream, Wq, Wk, Wv, Wt);
    hipLaunchKernelGGL(proj_qkv, dim3(512),   dim3(512), 0, stream, x, Wt, Q, K, Vt);
    hipLaunchKernelGGL(attn,     dim3(NTASK), dim3(256), 0, stream, Q, K, Vt,
                       Opart, Mpart, Lpart);
    hipLaunchKernelGGL(combine,  dim3(1024),  dim3(256), 0, stream,
                       Opart, Mpart, Lpart, out);
}

// Round 15
// 62.297 us; speedup vs baseline: 2.9726x; 1.0570x over previous
//
#include <hip/hip_runtime.h>
#include <hip/hip_bf16.h>

// ---------- types ----------
typedef __attribute__((ext_vector_type(8))) short bf16x8;   // 8 bf16 in 4 VGPRs
typedef __attribute__((ext_vector_type(4))) short bf16x4;   // 4 bf16 in 2 VGPRs
typedef __attribute__((ext_vector_type(4))) float f32x4;
typedef __attribute__((ext_vector_type(4))) int   i32x4;

#define C2LOG 0.18033688011112042f   // 0.125 * log2(e): folds 1/sqrt(64) + base-2
#define THR_RAW 44.3616f             // 8 / C2LOG : defer-max threshold (raw units)

// fp32 -> bf16 round-to-nearest-even (scalar)
__device__ __forceinline__ short f2bf(float f) {
    union { float f; unsigned u; } v; v.f = f;
    unsigned r = v.u + 0x7fff + ((v.u >> 16) & 1);
    return (short)(r >> 16);
}
// HW packed conversion: 2 fp32 -> u32 of 2 bf16 (RNE), one instruction
__device__ __forceinline__ unsigned cvtpk(float lo, float hi) {
    unsigned r;
    asm("v_cvt_pk_bf16_f32 %0, %1, %2" : "=v"(r) : "v"(lo), "v"(hi));
    return r;
}
__device__ __forceinline__ float bf2f(short s) {
    union { unsigned u; float f; } v; v.u = ((unsigned)(unsigned short)s) << 16;
    return v.f;
}
// pinned-order global 16B load; result NOT compiler-tracked -- every use
// must be behind a manual s_waitcnt vmcnt(N) (suffix argument, m135).
__device__ __forceinline__ float4 gload4(const float* p) {
    float4 r;
    asm volatile("global_load_dwordx4 %0, %1, off"
                 : "=&v"(r) : "v"(p) : "memory");
    return r;
}

// ---------- sizes ----------
#define BB 4
#define TT 4096
#define CC 1024
#define HD 64
#define NTASK_PB 144          // tasks per batch: sum_{g=0}^{7} 4*(g+1) = 144  (R9 split)
#define NTASK (BB * NTASK_PB) // 576

// =====================================================================
// Kernel 1: pack W q/k/v -> transposed bf16 Wt[192][1024], COALESCED
// (LDS transpose, pad 65).
// =====================================================================
__global__ __launch_bounds__(256) void prep_w(const float* __restrict__ Wq,
        const float* __restrict__ Wk, const float* __restrict__ Wv,
        short* __restrict__ Wt) {
    __shared__ float wls[64][65];
    const int w = blockIdx.x >> 4;            // 0..2
    const int c = blockIdx.x & 15;            // k-chunk
    const float* W = (w == 0) ? Wq : (w == 1) ? Wk : Wv;

    const int r  = threadIdx.x >> 4;          // 0..15
    const int q4 = threadIdx.x & 15;          // float4 col
    #pragma unroll
    for (int rr = 0; rr < 4; ++rr) {
        const int row = rr * 16 + r;          // 0..63 (k-local)
        float4 v = *reinterpret_cast<const float4*>(
            W + (size_t)(c * 64 + row) * HD + q4 * 4);
        wls[row][q4 * 4 + 0] = v.x;
        wls[row][q4 * 4 + 1] = v.y;
        wls[row][q4 * 4 + 2] = v.z;
        wls[row][q4 * 4 + 3] = v.w;
    }
    __syncthreads();

    const int n  = threadIdx.x >> 2;          // 0..63 (output row within W)
    const int ks = (threadIdx.x & 3) * 16;    // k-offset within chunk
    bf16x8 o0, o1;
    #pragma unroll
    for (int j = 0; j < 8; ++j) o0[j] = f2bf(wls[ks + j][n]);
    #pragma unroll
    for (int j = 0; j < 8; ++j) o1[j] = f2bf(wls[ks + 8 + j][n]);
    short* dst = Wt + (size_t)(w * 64 + n) * CC + c * 64 + ks;
    *reinterpret_cast<bf16x8*>(dst)     = o0;
    *reinterpret_cast<bf16x8*>(dst + 8) = o1;
}

// =====================================================================
// Kernel 2: QKV projection with 2-iteration x prefetch + counted vmcnt.
// Per iter: issue W(kc+1) DMA then x(kc+2) asm-load (pinned order) ->
// MFMA(kc) -> vmcnt(4|3)+sched_barrier -> CONV_X(x(kc+1)) ->
// vmcnt(1|0) + lgkmcnt(0) + raw s_barrier. The in-flight x-load
// survives the barrier (suffix-retirement argument, m135).
// =====================================================================
__global__ __launch_bounds__(512) void proj_qkv(const float* __restrict__ x,
        const short* __restrict__ Wt, short* __restrict__ Q,
        short* __restrict__ K, short* __restrict__ Vt) {
    __shared__ short xs[2][32 * 72];      // x tile bf16, pad-72 (reg-staged)
    __shared__ short wsm[2][192 * 64];    // W chunk bf16, 128B rows, XOR-swizzled

    const int tid  = threadIdx.x;
    const int lane = tid & 63;
    const int wv   = tid >> 6;
    const int lm   = lane & 15;
    const int lg   = lane >> 4;
    const int mhalf = wv & 1;
    const int ngrp  = wv >> 1;
    const int mbase = blockIdx.x * 32;

    const int xr  = tid >> 4;             // 0..31
    const int xq4 = tid & 15;             // float4 index within chunk
    const float* xrow = x + (size_t)(mbase + xr) * CC;

    int wsrow[3], wscol[3];
    #pragma unroll
    for (int it = 0; it < 3; ++it) {
        const int off = it * 8192 + wv * 1024 + lane * 16;
        wsrow[it] = off >> 7;
        wscol[it] = (off & 127) ^ ((wsrow[it] & 7) << 4);
    }

#define STAGE_W(bufidx, kc)                                                           \
    {                                                                                 \
        _Pragma("unroll")                                                             \
        for (int it = 0; it < 3; ++it) {                                              \
            const char* src = (const char*)(Wt + (size_t)wsrow[it] * CC + (kc) * 64)  \
                              + wscol[it];                                            \
            char* dst = (char*)&wsm[bufidx][0] + it * 8192 + wv * 1024;               \
            __builtin_amdgcn_global_load_lds(                                         \
                (const __attribute__((address_space(1))) unsigned*)src,               \
                (__attribute__((address_space(3))) unsigned*)dst, 16, 0, 0);          \
        }                                                                             \
    }

#define CONV_X(bufidx, xv)                                                            \
    {                                                                                 \
        int2 pk;                                                                      \
        pk.x = (int)cvtpk((xv).x, (xv).y);                                            \
        pk.y = (int)cvtpk((xv).z, (xv).w);                                            \
        *reinterpret_cast<int2*>(&xs[bufidx][xr * 72 + xq4 * 4]) = pk;                \
    }

    f32x4 acc[3];
    #pragma unroll
    for (int i = 0; i < 3; ++i) acc[i] = f32x4{0.f, 0.f, 0.f, 0.f};

    // ---- prologue: conv chunk0 into xs[0], stage W0, prefetch x(1) ----
    {
        float4 v = *reinterpret_cast<const float4*>(xrow + xq4 * 4);
        CONV_X(0, v)
        STAGE_W(0, 0)
    }
    float4 vA = gload4(xrow + 64 + xq4 * 4);           // x chunk 1, in flight
    asm volatile("s_waitcnt vmcnt(1)" ::: "memory");   // W0 done; vA may fly
    asm volatile("s_waitcnt lgkmcnt(0)" ::: "memory"); // xs[0] visible
    __builtin_amdgcn_s_barrier();

    const int arow = mhalf * 16 + lm;
    int buf = 0;
    for (int kc = 0; kc < 16; ++kc) {
        // ---- issue next W (DMA) then next-next x (pinned order) ----
        if (kc < 15) STAGE_W(buf ^ 1, kc + 1)
        float4 vB;
        if (kc < 14) vB = gload4(xrow + (kc + 2) * 64 + xq4 * 4);

        // ---- MFMA on current buffers ----
        bf16x8 a0 = *reinterpret_cast<const bf16x8*>(&xs[buf][arow * 72 + lg * 8]);
        bf16x8 a1 = *reinterpret_cast<const bf16x8*>(&xs[buf][arow * 72 + 32 + lg * 8]);
        #pragma unroll
        for (int c = 0; c < 3; ++c) {
            const int brow = (ngrp * 3 + c) * 16 + lm;
            const int sw = (brow & 7) << 4;
            bf16x8 b0 = *reinterpret_cast<const bf16x8*>(
                (const char*)&wsm[buf][0] + brow * 128 + ((lg * 16) ^ sw));
            bf16x8 b1 = *reinterpret_cast<const bf16x8*>(
                (const char*)&wsm[buf][0] + brow * 128 + ((64 + lg * 16) ^ sw));
            acc[c] = __builtin_amdgcn_mfma_f32_16x16x32_bf16(a0, b0, acc[c], 0, 0, 0);
            acc[c] = __builtin_amdgcn_mfma_f32_16x16x32_bf16(a1, b1, acc[c], 0, 0, 0);
        }

        // ---- convert x(kc+1) (vA): manual wait, then pin schedule ----
        if (kc < 15) {
            if (kc < 14) asm volatile("s_waitcnt vmcnt(4)" ::: "memory");
            else         asm volatile("s_waitcnt vmcnt(3)" ::: "memory");
            __builtin_amdgcn_sched_barrier(0);   // rule 18: no hoist past wait
            CONV_X(buf ^ 1, vA)
        }
        vA = vB;

        // ---- end-of-iter: W(kc+1) retired; x(kc+2) stays in flight ----
        if (kc < 15) {
            __builtin_amdgcn_sched_barrier(0);
            if (kc < 14) asm volatile("s_waitcnt vmcnt(1)" ::: "memory");
            else         asm volatile("s_waitcnt vmcnt(0)" ::: "memory");
            asm volatile("s_waitcnt lgkmcnt(0)" ::: "memory");
            __builtin_amdgcn_s_barrier();
        }
        buf ^= 1;
    }
#undef STAGE_W
#undef CONV_X

    const int mrow = mbase + mhalf * 16 + lg * 4;
    #pragma unroll
    for (int c = 0; c < 3; ++c) {
        const int cn = ngrp * 3 + c;
        if (cn < 4) {
            #pragma unroll
            for (int r = 0; r < 4; ++r)
                Q[(size_t)(mrow + r) * HD + cn * 16 + lm] = f2bf(acc[c][r]);
        } else if (cn < 8) {
            #pragma unroll
            for (int r = 0; r < 4; ++r)
                K[(size_t)(mrow + r) * HD + (cn - 4) * 16 + lm] = f2bf(acc[c][r]);
        } else {
            const int bb   = mbase >> 12;
            const int tloc = (mbase & 4095) + mhalf * 16 + lg * 4;
            int2 pk;
            pk.x = (int)cvtpk(acc[c][0], acc[c][1]);
            pk.y = (int)cvtpk(acc[c][2], acc[c][3]);
            *reinterpret_cast<int2*>(
                Vt + (size_t)bb * (HD * TT) + (size_t)((cn - 8) * 16 + lm) * TT + tloc) = pk;
        }
    }
}

// =====================================================================
// Kernel 3: causal flash attention (R14: triple-buffered KV, counted
// vmcnt, raw s_barrier, XCD-chunked task remap).
// =====================================================================
__global__ __launch_bounds__(256, 3) void attn(const short* __restrict__ Q,
        const short* __restrict__ K, const short* __restrict__ Vt,
        short* __restrict__ Opart, float* __restrict__ Mpart,
        float* __restrict__ Lpart) {
    __shared__ short ks[3][64 * 64];   // [buf][row=kv][d]  8KB each, swizzled
    __shared__ short vs[3][64 * 64];   // [buf][row=d][kv]  8KB each, swizzled

    const int tid  = threadIdx.x;
    const int lane = tid & 63;
    const int wv   = tid >> 6;            // 0..3
    const int lm   = lane & 15;
    const int lg   = lane >> 4;

    // ---- XCD-chunked remap, then task decode: task = b*144 + t ----
    const int task = (blockIdx.x & 7) * (NTASK / 8) + (blockIdx.x >> 3);
    const int b  = task / NTASK_PB;
    int t_in = task - b * NTASK_PB;
    int g = 0;
    while (t_in >= 2 * (g + 1) * (g + 2)) ++g;          // g = i>>2, <=7
    const int idx = t_in - 2 * g * (g + 1);
    const int i   = 4 * g + idx / (g + 1);              // q-block 0..31
    const int seg = idx % (g + 1);                      // segment 0..g
    const int S   = g + 1;                              // segments for this i
    const int niter = 2 * i + 2;                        // KV-64 tiles in prefix
    const int nloop = (niter - seg + S - 1) / S;        // >= 1, block-uniform

    const size_t qkb = (size_t)b * TT * HD;
    const size_t vtb = (size_t)b * HD * TT;
    const int qrow = i * 128 + wv * 32;                 // wave's first q-row
    const int tmax = (qrow + 31) >> 6;

    bf16x8 qf0 = *reinterpret_cast<const bf16x8*>(Q + qkb + (size_t)(qrow + lm) * HD + lg * 8);
    bf16x8 qf1 = *reinterpret_cast<const bf16x8*>(Q + qkb + (size_t)(qrow + lm) * HD + 32 + lg * 8);
    bf16x8 qf2 = *reinterpret_cast<const bf16x8*>(Q + qkb + (size_t)(qrow + 16 + lm) * HD + lg * 8);
    bf16x8 qf3 = *reinterpret_cast<const bf16x8*>(Q + qkb + (size_t)(qrow + 16 + lm) * HD + 32 + lg * 8);

    f32x4 oA[4], oB[4];
    #pragma unroll
    for (int c = 0; c < 4; ++c) { oA[c] = f32x4{0.f,0.f,0.f,0.f}; oB[c] = f32x4{0.f,0.f,0.f,0.f}; }
    float mrunA = -1e30f, lrunA = 0.f;   // RAW units
    float mrunB = -1e30f, lrunB = 0.f;

    const int srcA = lm + ((lane & 16) << 1);
    const int srcB = srcA + 16;
    const bool hihalf = (lane & 32) != 0;

    int srow[2], scol[2];
    #pragma unroll
    for (int c = 0; c < 2; ++c) {
        const int off = wv * 2048 + c * 1024 + lane * 16;
        srow[c] = off >> 7;
        scol[c] = (off & 127) ^ ((srow[c] & 7) << 4);
    }

#define STAGE_KV(bufidx, tt)                                                          \
    {                                                                                 \
        _Pragma("unroll")                                                             \
        for (int c = 0; c < 2; ++c) {                                                 \
            const char* ksrc = (const char*)(K + qkb) + (tt) * 8192                   \
                               + (srow[c] << 7) + scol[c];                            \
            char* kdst = (char*)&ks[bufidx][0] + wv * 2048 + c * 1024;                \
            __builtin_amdgcn_global_load_lds(                                         \
                (const __attribute__((address_space(1))) unsigned*)ksrc,              \
                (__attribute__((address_space(3))) unsigned*)kdst, 16, 0, 0);         \
            const char* vsrc = (const char*)(Vt + vtb) + (size_t)srow[c] * (TT * 2)   \
                               + (tt) * 128 + scol[c];                                \
            char* vdst = (char*)&vs[bufidx][0] + wv * 2048 + c * 1024;                \
            __builtin_amdgcn_global_load_lds(                                         \
                (const __attribute__((address_space(1))) unsigned*)vsrc,              \
                (__attribute__((address_space(3))) unsigned*)vdst, 16, 0, 0);         \
        }                                                                             \
    }

    // ---- prologue: stage tiles 0 and 1 (if any); wait only for tile 0 ----
    STAGE_KV(0, seg)
    if (nloop > 1) {
        STAGE_KV(1, seg + S)
        asm volatile("s_waitcnt vmcnt(4)" ::: "memory");
    } else {
        asm volatile("s_waitcnt vmcnt(0)" ::: "memory");
    }
    __builtin_amdgcn_s_barrier();

    for (int n = 0; n < nloop; ++n) {
        const int t = seg + n * S;
        const bool stage2 = (n + 2 < nloop);            // block-uniform
        if (stage2) STAGE_KV((n + 2) % 3, t + 2 * S)

        if (t <= tmax) {
            const short* ksb = &ks[n % 3][0];
            const short* vsb = &vs[n % 3][0];
            const int kv = t * 64;

            // ---- QK^T swapped, both sub-tiles share k0/k1 (RAW scores) ----
            f32x4 stA[4], stB[4];
            #pragma unroll
            for (int kt = 0; kt < 4; ++kt) {
                const int krow = kt * 16 + lm;
                const int sw = (krow & 7) << 4;
                bf16x8 k0 = *reinterpret_cast<const bf16x8*>(
                    (const char*)ksb + krow * 128 + ((lg * 16) ^ sw));
                bf16x8 k1 = *reinterpret_cast<const bf16x8*>(
                    (const char*)ksb + krow * 128 + ((64 + lg * 16) ^ sw));
                f32x4 a = f32x4{0.f,0.f,0.f,0.f};
                a = __builtin_amdgcn_mfma_f32_16x16x32_bf16(k0, qf0, a, 0, 0, 0);
                a = __builtin_amdgcn_mfma_f32_16x16x32_bf16(k1, qf1, a, 0, 0, 0);
                stA[kt] = a;
                f32x4 bb2 = f32x4{0.f,0.f,0.f,0.f};
                bb2 = __builtin_amdgcn_mfma_f32_16x16x32_bf16(k0, qf2, bb2, 0, 0, 0);
                bb2 = __builtin_amdgcn_mfma_f32_16x16x32_bf16(k1, qf3, bb2, 0, 0, 0);
                stB[kt] = bb2;
            }

            // ---- causal mask on raw scores (diag tiles only) ----
            if (kv + 63 > qrow) {
                const int qgA = qrow + lm;
                const int qgB = qrow + 16 + lm;
                #pragma unroll
                for (int kt = 0; kt < 4; ++kt)
                    #pragma unroll
                    for (int r = 0; r < 4; ++r) {
                        const int kk = kv + kt * 16 + lg * 4 + r;
                        if (kk > qgA) stA[kt][r] = -1e30f;
                        if (kk > qgB) stB[kt][r] = -1e30f;
                    }
            }

            // ---- tile max (tree, then 2 shfl) ----
            float mA0 = fmaxf(fmaxf(stA[0][0], stA[0][1]), fmaxf(stA[0][2], stA[0][3]));
            float mA1 = fmaxf(fmaxf(stA[1][0], stA[1][1]), fmaxf(stA[1][2], stA[1][3]));
            float mA2 = fmaxf(fmaxf(stA[2][0], stA[2][1]), fmaxf(stA[2][2], stA[2][3]));
            float mA3 = fmaxf(fmaxf(stA[3][0], stA[3][1]), fmaxf(stA[3][2], stA[3][3]));
            float mlocA = fmaxf(fmaxf(mA0, mA1), fmaxf(mA2, mA3));
            float mB0 = fmaxf(fmaxf(stB[0][0], stB[0][1]), fmaxf(stB[0][2], stB[0][3]));
            float mB1 = fmaxf(fmaxf(stB[1][0], stB[1][1]), fmaxf(stB[1][2], stB[1][3]));
            float mB2 = fmaxf(fmaxf(stB[2][0], stB[2][1]), fmaxf(stB[2][2], stB[2][3]));
            float mB3 = fmaxf(fmaxf(stB[3][0], stB[3][1]), fmaxf(stB[3][2], stB[3][3]));
            float mlocB = fmaxf(fmaxf(mB0, mB1), fmaxf(mB2, mB3));
            mlocA = fmaxf(mlocA, __shfl_xor(mlocA, 16));
            mlocA = fmaxf(mlocA, __shfl_xor(mlocA, 32));
            mlocB = fmaxf(mlocB, __shfl_xor(mlocB, 16));
            mlocB = fmaxf(mlocB, __shfl_xor(mlocB, 32));

            // ---- defer-max: rescale only when max grew past threshold ----
            if (!__all(mlocA <= mrunA + THR_RAW)) {
                const float mnewA = fmaxf(mrunA, mlocA);
                const float alphaA = __builtin_amdgcn_exp2f((mrunA - mnewA) * C2LOG);
                mrunA = mnewA;
                lrunA *= alphaA;
                #pragma unroll
                for (int c = 0; c < 4; ++c)
                    #pragma unroll
                    for (int r = 0; r < 4; ++r) oA[c][r] *= alphaA;
            }
            if (!__all(mlocB <= mrunB + THR_RAW)) {
                const float mnewB = fmaxf(mrunB, mlocB);
                const float alphaB = __builtin_amdgcn_exp2f((mrunB - mnewB) * C2LOG);
                mrunB = mnewB;
                lrunB *= alphaB;
                #pragma unroll
                for (int c = 0; c < 4; ++c)
                    #pragma unroll
                    for (int r = 0; r < 4; ++r) oB[c][r] *= alphaB;
            }

            // ---- p = exp2(fma(st, C2LOG, -m*C2LOG)) ----
            const float ncA = -mrunA * C2LOG;
            const float ncB = -mrunB * C2LOG;
            float pA[4][4], pB[4][4];
            float rsA = 0.f, rsB = 0.f;
            #pragma unroll
            for (int kt = 0; kt < 4; ++kt)
                #pragma unroll
                for (int r = 0; r < 4; ++r) {
                    pA[kt][r] = __builtin_amdgcn_exp2f(__builtin_fmaf(stA[kt][r], C2LOG, ncA));
                    rsA += pA[kt][r];
                    pB[kt][r] = __builtin_amdgcn_exp2f(__builtin_fmaf(stB[kt][r], C2LOG, ncB));
                    rsB += pB[kt][r];
                }
            rsA += __shfl_xor(rsA, 16); rsA += __shfl_xor(rsA, 32);
            rsB += __shfl_xor(rsB, 16); rsB += __shfl_xor(rsB, 32);
            lrunA += rsA;
            lrunB += rsB;

            // ---- pack P^T to bf16 pairs (HW cvt_pk) ----
            unsigned uA[4][2], uB[4][2];
            #pragma unroll
            for (int kt = 0; kt < 4; ++kt) {
                uA[kt][0] = cvtpk(pA[kt][0], pA[kt][1]);
                uA[kt][1] = cvtpk(pA[kt][2], pA[kt][3]);
                uB[kt][0] = cvtpk(pB[kt][0], pB[kt][1]);
                uB[kt][1] = cvtpk(pB[kt][2], pB[kt][3]);
            }

            // ---- PV: both sub-tiles share va reads ----
            #pragma unroll
            for (int h = 0; h < 2; ++h) {
                const int a0 = __shfl((int)uA[2*h][0],   srcA);
                const int a1c = __shfl((int)uA[2*h+1][0], srcA);
                const int a2 = __shfl((int)uA[2*h][1],   srcA);
                const int a3c = __shfl((int)uA[2*h+1][1], srcA);
                const int a4 = __shfl((int)uA[2*h][0],   srcB);
                const int a5c = __shfl((int)uA[2*h+1][0], srcB);
                const int a6 = __shfl((int)uA[2*h][1],   srcB);
                const int a7c = __shfl((int)uA[2*h+1][1], srcB);
                union { i32x4 iv; bf16x8 v; } cvA;
                cvA.iv = i32x4{ hihalf ? a1c : a0, hihalf ? a3c : a2,
                                hihalf ? a5c : a4, hihalf ? a7c : a6 };
                const int b0 = __shfl((int)uB[2*h][0],   srcA);
                const int b1c = __shfl((int)uB[2*h+1][0], srcA);
                const int b2 = __shfl((int)uB[2*h][1],   srcA);
                const int b3c = __shfl((int)uB[2*h+1][1], srcA);
                const int b4 = __shfl((int)uB[2*h][0],   srcB);
                const int b5c = __shfl((int)uB[2*h+1][0], srcB);
                const int b6 = __shfl((int)uB[2*h][1],   srcB);
                const int b7c = __shfl((int)uB[2*h+1][1], srcB);
                union { i32x4 iv; bf16x8 v; } cvB;
                cvB.iv = i32x4{ hihalf ? b1c : b0, hihalf ? b3c : b2,
                                hihalf ? b5c : b4, hihalf ? b7c : b6 };
                #pragma unroll
                for (int c = 0; c < 4; ++c) {
                    const int vrow = c * 16 + lm;
                    const int sw = (vrow & 7) << 4;
                    bf16x8 va = *reinterpret_cast<const bf16x8*>(
                        (const char*)vsb + vrow * 128 + ((h * 64 + lg * 16) ^ sw));
                    oA[c] = __builtin_amdgcn_mfma_f32_16x16x32_bf16(va, cvA.v, oA[c], 0, 0, 0);
                    oB[c] = __builtin_amdgcn_mfma_f32_16x16x32_bf16(va, cvB.v, oB[c], 0, 0, 0);
                }
            }
        }

        // ---- counted drain: wait only for next-needed buffer's stage ----
        __builtin_amdgcn_sched_barrier(0);
        asm volatile("s_waitcnt lgkmcnt(0)" ::: "memory");
        if (stage2) asm volatile("s_waitcnt vmcnt(4)" ::: "memory");
        else        asm volatile("s_waitcnt vmcnt(0)" ::: "memory");
        __builtin_amdgcn_s_barrier();
    }
#undef STAGE_KV

    // ---- write partials: O bf16 (task,row,d), m (RAW)/l fp32 ----
    short* Ob = Opart + (size_t)task * (128 * HD);
    #pragma unroll
    for (int c = 0; c < 4; ++c) {
        int2 pkA, pkB;
        pkA.x = (int)cvtpk(oA[c][0], oA[c][1]);
        pkA.y = (int)cvtpk(oA[c][2], oA[c][3]);
        pkB.x = (int)cvtpk(oB[c][0], oB[c][1]);
        pkB.y = (int)cvtpk(oB[c][2], oB[c][3]);
        *reinterpret_cast<int2*>(&Ob[(wv * 32 + lm) * HD + c * 16 + lg * 4]) = pkA;
        *reinterpret_cast<int2*>(&Ob[(wv * 32 + 16 + lm) * HD + c * 16 + lg * 4]) = pkB;
    }
    if (lg == 0) {
        Mpart[task * 128 + wv * 32 + lm] = mrunA;
        Lpart[task * 128 + wv * 32 + lm] = lrunA;
        Mpart[task * 128 + wv * 32 + 16 + lm] = mrunB;
        Lpart[task * 128 + wv * 32 + 16 + lm] = lrunB;
    }
}

// =====================================================================
// Kernel 4: combine partials -> fp32 out (R9 version; Mpart RAW units).
// =====================================================================
__global__ __launch_bounds__(256) void combine(const short* __restrict__ Opart,
        const float* __restrict__ Mpart, const float* __restrict__ Lpart,
        float* __restrict__ out) {
    const int b   = blockIdx.x >> 8;
    const int rem = blockIdx.x & 255;
    const int i   = rem >> 3;
    const int rr  = rem & 7;
    const int g = i >> 2;
    const int S = g + 1;
    const int task0 = b * NTASK_PB + 2 * g * (g + 1) + (i - 4 * g) * (g + 1);
    const int qbase = i * 128;

    const int tid = threadIdx.x;
    const int row = rr * 16 + (tid >> 4);   // 0..127
    const int cb  = (tid & 15) << 2;        // col (x4 floats)

    float mmax = -1e30f;
    float ms[8];
    for (int s = 0; s < S; ++s) {
        ms[s] = Mpart[(task0 + s) * 128 + row];
        mmax = fmaxf(mmax, ms[s]);
    }
    float lsum = 0.f;
    float a0 = 0.f, a1 = 0.f, a2 = 0.f, a3 = 0.f;
    for (int s = 0; s < S; ++s) {
        const float w = __builtin_amdgcn_exp2f((ms[s] - mmax) * C2LOG);
        lsum += Lpart[(task0 + s) * 128 + row] * w;
        bf16x4 ov = *reinterpret_cast<const bf16x4*>(
            &Opart[((size_t)(task0 + s) * 128 + row) * HD + cb]);
        a0 += bf2f(ov[0]) * w;
        a1 += bf2f(ov[1]) * w;
        a2 += bf2f(ov[2]) * w;
        a3 += bf2f(ov[3]) * w;
    }
    const float inv = 1.0f / lsum;
    f32x4 res{ a0 * inv, a1 * inv, a2 * inv, a3 * inv };
    *reinterpret_cast<f32x4*>(
        &out[((size_t)b * TT + qbase + row) * HD + cb]) = res;
}

// =====================================================================
extern "C" void kernel_launch(void* const* d_in, const int* in_sizes, int n_in,
                              void* d_out, int out_size, void* d_ws, size_t ws_size,
                              hipStream_t stream) {
    const float* x  = (const float*)d_in[0];
    const float* Wq = (const float*)d_in[1];
    const float* Wk = (const float*)d_in[2];
    const float* Wv = (const float*)d_in[3];
    float* out = (float*)d_out;

    char* ws = (char*)d_ws;
    short* Wt    = (short*)(ws);                          // 393216 B
    short* Q     = (short*)(ws + 393216);                 // 2097152 B
    short* K     = (short*)(ws + 2490368);                // 2097152 B
    short* Vt    = (short*)(ws + 4587520);                // 2097152 B
    short* Opart = (short*)(ws + 6684672);                // 576*128*64*2 = 9437184 B
    float* Mpart = (float*)(ws + 16121856);               // 294912 B
    float* Lpart = (float*)(ws + 16416768);               // 294912 B
    // total: ~16.7 MiB (ws is ~268 MB per harness poison fills)

    hipLaunchKernelGGL(prep_w,   dim3(48),    dim3(256), 0, stream, Wq, Wk, Wv, Wt);
    hipLaunchKernelGGL(proj_qkv, dim3(512),   dim3(512), 0, stream, x, Wt, Q, K, Vt);
    hipLaunchKernelGGL(attn,     dim3(NTASK), dim3(256), 0, stream, Q, K, Vt,
                       Opart, Mpart, Lpart);
    hipLaunchKernelGGL(combine,  dim3(1024),  dim3(256), 0, stream,
                       Opart, Mpart, Lpart, out);
}

// Round 17
// 60.997 us; speedup vs baseline: 3.0360x; 1.0213x over previous
//
#include <hip/hip_runtime.h>
#include <hip/hip_bf16.h>

// ---------- types ----------
typedef __attribute__((ext_vector_type(8))) short bf16x8;   // 8 bf16 in 4 VGPRs
typedef __attribute__((ext_vector_type(4))) short bf16x4;   // 4 bf16 in 2 VGPRs
typedef __attribute__((ext_vector_type(4))) float f32x4;
typedef __attribute__((ext_vector_type(4))) int   i32x4;

#define C2LOG 0.18033688011112042f   // 0.125 * log2(e): folds 1/sqrt(64) + base-2
#define THR_RAW 44.3616f             // 8 / C2LOG : defer-max threshold (raw units)

// fp32 -> bf16 round-to-nearest-even (scalar)
__device__ __forceinline__ short f2bf(float f) {
    union { float f; unsigned u; } v; v.f = f;
    unsigned r = v.u + 0x7fff + ((v.u >> 16) & 1);
    return (short)(r >> 16);
}
// HW packed conversion: 2 fp32 -> u32 of 2 bf16 (RNE), one instruction
__device__ __forceinline__ unsigned cvtpk(float lo, float hi) {
    unsigned r;
    asm("v_cvt_pk_bf16_f32 %0, %1, %2" : "=v"(r) : "v"(lo), "v"(hi));
    return r;
}
__device__ __forceinline__ float bf2f(short s) {
    union { unsigned u; float f; } v; v.u = ((unsigned)(unsigned short)s) << 16;
    return v.f;
}
// pinned-order global 16B load; result used only behind manual vmcnt waits.
__device__ __forceinline__ float4 gload4(const float* p) {
    float4 r;
    asm volatile("global_load_dwordx4 %0, %1, off"
                 : "=&v"(r) : "v"(p) : "memory");
    return r;
}

// ---------- sizes ----------
#define BB 4
#define TT 4096
#define CC 1024
#define HD 64
#define NTASK_PB 144          // tasks per batch (R9 split: S_i = i/4 + 1)
#define NTASK (BB * NTASK_PB) // 576

// =====================================================================
// Kernel 1: pack W q/k/v -> transposed bf16 Wt[192][1024], COALESCED
// (LDS transpose, pad 65).
// =====================================================================
__global__ __launch_bounds__(256) void prep_w(const float* __restrict__ Wq,
        const float* __restrict__ Wk, const float* __restrict__ Wv,
        short* __restrict__ Wt) {
    __shared__ float wls[64][65];
    const int w = blockIdx.x >> 4;            // 0..2
    const int c = blockIdx.x & 15;            // k-chunk
    const float* W = (w == 0) ? Wq : (w == 1) ? Wk : Wv;

    const int r  = threadIdx.x >> 4;          // 0..15
    const int q4 = threadIdx.x & 15;          // float4 col
    #pragma unroll
    for (int rr = 0; rr < 4; ++rr) {
        const int row = rr * 16 + r;          // 0..63 (k-local)
        float4 v = *reinterpret_cast<const float4*>(
            W + (size_t)(c * 64 + row) * HD + q4 * 4);
        wls[row][q4 * 4 + 0] = v.x;
        wls[row][q4 * 4 + 1] = v.y;
        wls[row][q4 * 4 + 2] = v.z;
        wls[row][q4 * 4 + 3] = v.w;
    }
    __syncthreads();

    const int n  = threadIdx.x >> 2;          // 0..63 (output row within W)
    const int ks = (threadIdx.x & 3) * 16;    // k-offset within chunk
    bf16x8 o0, o1;
    #pragma unroll
    for (int j = 0; j < 8; ++j) o0[j] = f2bf(wls[ks + j][n]);
    #pragma unroll
    for (int j = 0; j < 8; ++j) o1[j] = f2bf(wls[ks + 8 + j][n]);
    short* dst = Wt + (size_t)(w * 64 + n) * CC + c * 64 + ks;
    *reinterpret_cast<bf16x8*>(dst)     = o0;
    *reinterpret_cast<bf16x8*>(dst + 8) = o1;
}

// =====================================================================
// Kernel 2: QKV projection (R15: xs LDS staging, W DMA double-buffer,
// 2-iteration x prefetch + counted vmcnt, raw s_barrier).
// =====================================================================
__global__ __launch_bounds__(512) void proj_qkv(const float* __restrict__ x,
        const short* __restrict__ Wt, short* __restrict__ Q,
        short* __restrict__ K, short* __restrict__ Vt) {
    __shared__ short xs[2][32 * 72];      // x tile bf16, pad-72 (reg-staged)
    __shared__ short wsm[2][192 * 64];    // W chunk bf16, 128B rows, XOR-swizzled

    const int tid  = threadIdx.x;
    const int lane = tid & 63;
    const int wv   = tid >> 6;
    const int lm   = lane & 15;
    const int lg   = lane >> 4;
    const int mhalf = wv & 1;
    const int ngrp  = wv >> 1;
    const int mbase = blockIdx.x * 32;

    const int xr  = tid >> 4;             // 0..31
    const int xq4 = tid & 15;             // float4 index within chunk
    const float* xrow = x + (size_t)(mbase + xr) * CC;

    int wsrow[3], wscol[3];
    #pragma unroll
    for (int it = 0; it < 3; ++it) {
        const int off = it * 8192 + wv * 1024 + lane * 16;
        wsrow[it] = off >> 7;
        wscol[it] = (off & 127) ^ ((wsrow[it] & 7) << 4);
    }

#define STAGE_W(bufidx, kc)                                                           \
    {                                                                                 \
        _Pragma("unroll")                                                             \
        for (int it = 0; it < 3; ++it) {                                              \
            const char* src = (const char*)(Wt + (size_t)wsrow[it] * CC + (kc) * 64)  \
                              + wscol[it];                                            \
            char* dst = (char*)&wsm[bufidx][0] + it * 8192 + wv * 1024;               \
            __builtin_amdgcn_global_load_lds(                                         \
                (const __attribute__((address_space(1))) unsigned*)src,               \
                (__attribute__((address_space(3))) unsigned*)dst, 16, 0, 0);          \
        }                                                                             \
    }

#define CONV_X(bufidx, xv)                                                            \
    {                                                                                 \
        int2 pk;                                                                      \
        pk.x = (int)cvtpk((xv).x, (xv).y);                                            \
        pk.y = (int)cvtpk((xv).z, (xv).w);                                            \
        *reinterpret_cast<int2*>(&xs[bufidx][xr * 72 + xq4 * 4]) = pk;                \
    }

    f32x4 acc[3];
    #pragma unroll
    for (int i = 0; i < 3; ++i) acc[i] = f32x4{0.f, 0.f, 0.f, 0.f};

    // ---- prologue: conv chunk0 into xs[0], stage W0, prefetch x(1) ----
    {
        float4 v = *reinterpret_cast<const float4*>(xrow + xq4 * 4);
        CONV_X(0, v)
        STAGE_W(0, 0)
    }
    float4 vA = gload4(xrow + 64 + xq4 * 4);           // x chunk 1, in flight
    asm volatile("s_waitcnt vmcnt(1)" ::: "memory");   // W0 done; vA may fly
    asm volatile("s_waitcnt lgkmcnt(0)" ::: "memory"); // xs[0] visible
    __builtin_amdgcn_s_barrier();

    const int arow = mhalf * 16 + lm;
    int buf = 0;
    for (int kc = 0; kc < 16; ++kc) {
        // ---- issue next W (DMA) then next-next x (pinned order) ----
        if (kc < 15) STAGE_W(buf ^ 1, kc + 1)
        float4 vB;
        if (kc < 14) vB = gload4(xrow + (kc + 2) * 64 + xq4 * 4);

        // ---- MFMA on current buffers ----
        bf16x8 a0 = *reinterpret_cast<const bf16x8*>(&xs[buf][arow * 72 + lg * 8]);
        bf16x8 a1 = *reinterpret_cast<const bf16x8*>(&xs[buf][arow * 72 + 32 + lg * 8]);
        #pragma unroll
        for (int c = 0; c < 3; ++c) {
            const int brow = (ngrp * 3 + c) * 16 + lm;
            const int sw = (brow & 7) << 4;
            bf16x8 b0 = *reinterpret_cast<const bf16x8*>(
                (const char*)&wsm[buf][0] + brow * 128 + ((lg * 16) ^ sw));
            bf16x8 b1 = *reinterpret_cast<const bf16x8*>(
                (const char*)&wsm[buf][0] + brow * 128 + ((64 + lg * 16) ^ sw));
            acc[c] = __builtin_amdgcn_mfma_f32_16x16x32_bf16(a0, b0, acc[c], 0, 0, 0);
            acc[c] = __builtin_amdgcn_mfma_f32_16x16x32_bf16(a1, b1, acc[c], 0, 0, 0);
        }

        // ---- convert x(kc+1) (vA): manual wait, then pin schedule ----
        if (kc < 15) {
            if (kc < 14) asm volatile("s_waitcnt vmcnt(4)" ::: "memory");
            else         asm volatile("s_waitcnt vmcnt(3)" ::: "memory");
            __builtin_amdgcn_sched_barrier(0);   // rule 18: no hoist past wait
            CONV_X(buf ^ 1, vA)
        }
        vA = vB;

        // ---- end-of-iter: W(kc+1) retired; x(kc+2) stays in flight ----
        if (kc < 15) {
            __builtin_amdgcn_sched_barrier(0);
            if (kc < 14) asm volatile("s_waitcnt vmcnt(1)" ::: "memory");
            else         asm volatile("s_waitcnt vmcnt(0)" ::: "memory");
            asm volatile("s_waitcnt lgkmcnt(0)" ::: "memory");
            __builtin_amdgcn_s_barrier();
        }
        buf ^= 1;
    }
#undef STAGE_W
#undef CONV_X

    const int mrow = mbase + mhalf * 16 + lg * 4;
    #pragma unroll
    for (int c = 0; c < 3; ++c) {
        const int cn = ngrp * 3 + c;
        if (cn < 4) {
            #pragma unroll
            for (int r = 0; r < 4; ++r)
                Q[(size_t)(mrow + r) * HD + cn * 16 + lm] = f2bf(acc[c][r]);
        } else if (cn < 8) {
            #pragma unroll
            for (int r = 0; r < 4; ++r)
                K[(size_t)(mrow + r) * HD + (cn - 4) * 16 + lm] = f2bf(acc[c][r]);
        } else {
            const int bb   = mbase >> 12;
            const int tloc = (mbase & 4095) + mhalf * 16 + lg * 4;
            int2 pk;
            pk.x = (int)cvtpk(acc[c][0], acc[c][1]);
            pk.y = (int)cvtpk(acc[c][2], acc[c][3]);
            *reinterpret_cast<int2*>(
                Vt + (size_t)bb * (HD * TT) + (size_t)((cn - 8) * 16 + lm) * TT + tloc) = pk;
        }
    }
}

// =====================================================================
// Kernel 3: causal flash attention (R15: triple-buffered KV, counted
// vmcnt, raw s_barrier, XCD-chunked task remap) + T5 s_setprio around
// the two MFMA clusters (counted-vmcnt loop has wave role diversity).
// =====================================================================
__global__ __launch_bounds__(256, 3) void attn(const short* __restrict__ Q,
        const short* __restrict__ K, const short* __restrict__ Vt,
        short* __restrict__ Opart, float* __restrict__ Mpart,
        float* __restrict__ Lpart) {
    __shared__ short ks[3][64 * 64];   // [buf][row=kv][d]  8KB each, swizzled
    __shared__ short vs[3][64 * 64];   // [buf][row=d][kv]  8KB each, swizzled

    const int tid  = threadIdx.x;
    const int lane = tid & 63;
    const int wv   = tid >> 6;            // 0..3
    const int lm   = lane & 15;
    const int lg   = lane >> 4;

    // ---- XCD-chunked remap, then task decode: task = b*144 + t ----
    const int task = (blockIdx.x & 7) * (NTASK / 8) + (blockIdx.x >> 3);
    const int b  = task / NTASK_PB;
    int t_in = task - b * NTASK_PB;
    int g = 0;
    while (t_in >= 2 * (g + 1) * (g + 2)) ++g;          // g = i>>2, <=7
    const int idx = t_in - 2 * g * (g + 1);
    const int i   = 4 * g + idx / (g + 1);              // q-block 0..31
    const int seg = idx % (g + 1);                      // segment 0..g
    const int S   = g + 1;                              // segments for this i
    const int niter = 2 * i + 2;                        // KV-64 tiles in prefix
    const int nloop = (niter - seg + S - 1) / S;        // >= 1, block-uniform

    const size_t qkb = (size_t)b * TT * HD;
    const size_t vtb = (size_t)b * HD * TT;
    const int qrow = i * 128 + wv * 32;                 // wave's first q-row
    const int tmax = (qrow + 31) >> 6;

    bf16x8 qf0 = *reinterpret_cast<const bf16x8*>(Q + qkb + (size_t)(qrow + lm) * HD + lg * 8);
    bf16x8 qf1 = *reinterpret_cast<const bf16x8*>(Q + qkb + (size_t)(qrow + lm) * HD + 32 + lg * 8);
    bf16x8 qf2 = *reinterpret_cast<const bf16x8*>(Q + qkb + (size_t)(qrow + 16 + lm) * HD + lg * 8);
    bf16x8 qf3 = *reinterpret_cast<const bf16x8*>(Q + qkb + (size_t)(qrow + 16 + lm) * HD + 32 + lg * 8);

    f32x4 oA[4], oB[4];
    #pragma unroll
    for (int c = 0; c < 4; ++c) { oA[c] = f32x4{0.f,0.f,0.f,0.f}; oB[c] = f32x4{0.f,0.f,0.f,0.f}; }
    float mrunA = -1e30f, lrunA = 0.f;   // RAW units
    float mrunB = -1e30f, lrunB = 0.f;

    const int srcA = lm + ((lane & 16) << 1);
    const int srcB = srcA + 16;
    const bool hihalf = (lane & 32) != 0;

    int srow[2], scol[2];
    #pragma unroll
    for (int c = 0; c < 2; ++c) {
        const int off = wv * 2048 + c * 1024 + lane * 16;
        srow[c] = off >> 7;
        scol[c] = (off & 127) ^ ((srow[c] & 7) << 4);
    }

#define STAGE_KV(bufidx, tt)                                                          \
    {                                                                                 \
        _Pragma("unroll")                                                             \
        for (int c = 0; c < 2; ++c) {                                                 \
            const char* ksrc = (const char*)(K + qkb) + (tt) * 8192                   \
                               + (srow[c] << 7) + scol[c];                            \
            char* kdst = (char*)&ks[bufidx][0] + wv * 2048 + c * 1024;                \
            __builtin_amdgcn_global_load_lds(                                         \
                (const __attribute__((address_space(1))) unsigned*)ksrc,              \
                (__attribute__((address_space(3))) unsigned*)kdst, 16, 0, 0);         \
            const char* vsrc = (const char*)(Vt + vtb) + (size_t)srow[c] * (TT * 2)   \
                               + (tt) * 128 + scol[c];                                \
            char* vdst = (char*)&vs[bufidx][0] + wv * 2048 + c * 1024;                \
            __builtin_amdgcn_global_load_lds(                                         \
                (const __attribute__((address_space(1))) unsigned*)vsrc,              \
                (__attribute__((address_space(3))) unsigned*)vdst, 16, 0, 0);         \
        }                                                                             \
    }

    // ---- prologue: stage tiles 0 and 1 (if any); wait only for tile 0 ----
    STAGE_KV(0, seg)
    if (nloop > 1) {
        STAGE_KV(1, seg + S)
        asm volatile("s_waitcnt vmcnt(4)" ::: "memory");
    } else {
        asm volatile("s_waitcnt vmcnt(0)" ::: "memory");
    }
    __builtin_amdgcn_s_barrier();

    for (int n = 0; n < nloop; ++n) {
        const int t = seg + n * S;
        const bool stage2 = (n + 2 < nloop);            // block-uniform
        if (stage2) STAGE_KV((n + 2) % 3, t + 2 * S)

        if (t <= tmax) {
            const short* ksb = &ks[n % 3][0];
            const short* vsb = &vs[n % 3][0];
            const int kv = t * 64;

            // ---- QK^T swapped, both sub-tiles share k0/k1 (RAW scores) ----
            f32x4 stA[4], stB[4];
            __builtin_amdgcn_s_setprio(1);
            #pragma unroll
            for (int kt = 0; kt < 4; ++kt) {
                const int krow = kt * 16 + lm;
                const int sw = (krow & 7) << 4;
                bf16x8 k0 = *reinterpret_cast<const bf16x8*>(
                    (const char*)ksb + krow * 128 + ((lg * 16) ^ sw));
                bf16x8 k1 = *reinterpret_cast<const bf16x8*>(
                    (const char*)ksb + krow * 128 + ((64 + lg * 16) ^ sw));
                f32x4 a = f32x4{0.f,0.f,0.f,0.f};
                a = __builtin_amdgcn_mfma_f32_16x16x32_bf16(k0, qf0, a, 0, 0, 0);
                a = __builtin_amdgcn_mfma_f32_16x16x32_bf16(k1, qf1, a, 0, 0, 0);
                stA[kt] = a;
                f32x4 bb2 = f32x4{0.f,0.f,0.f,0.f};
                bb2 = __builtin_amdgcn_mfma_f32_16x16x32_bf16(k0, qf2, bb2, 0, 0, 0);
                bb2 = __builtin_amdgcn_mfma_f32_16x16x32_bf16(k1, qf3, bb2, 0, 0, 0);
                stB[kt] = bb2;
            }
            __builtin_amdgcn_s_setprio(0);

            // ---- causal mask on raw scores (diag tiles only) ----
            if (kv + 63 > qrow) {
                const int qgA = qrow + lm;
                const int qgB = qrow + 16 + lm;
                #pragma unroll
                for (int kt = 0; kt < 4; ++kt)
                    #pragma unroll
                    for (int r = 0; r < 4; ++r) {
                        const int kk = kv + kt * 16 + lg * 4 + r;
                        if (kk > qgA) stA[kt][r] = -1e30f;
                        if (kk > qgB) stB[kt][r] = -1e30f;
                    }
            }

            // ---- tile max (tree, then 2 shfl) ----
            float mA0 = fmaxf(fmaxf(stA[0][0], stA[0][1]), fmaxf(stA[0][2], stA[0][3]));
            float mA1 = fmaxf(fmaxf(stA[1][0], stA[1][1]), fmaxf(stA[1][2], stA[1][3]));
            float mA2 = fmaxf(fmaxf(stA[2][0], stA[2][1]), fmaxf(stA[2][2], stA[2][3]));
            float mA3 = fmaxf(fmaxf(stA[3][0], stA[3][1]), fmaxf(stA[3][2], stA[3][3]));
            float mlocA = fmaxf(fmaxf(mA0, mA1), fmaxf(mA2, mA3));
            float mB0 = fmaxf(fmaxf(stB[0][0], stB[0][1]), fmaxf(stB[0][2], stB[0][3]));
            float mB1 = fmaxf(fmaxf(stB[1][0], stB[1][1]), fmaxf(stB[1][2], stB[1][3]));
            float mB2 = fmaxf(fmaxf(stB[2][0], stB[2][1]), fmaxf(stB[2][2], stB[2][3]));
            float mB3 = fmaxf(fmaxf(stB[3][0], stB[3][1]), fmaxf(stB[3][2], stB[3][3]));
            float mlocB = fmaxf(fmaxf(mB0, mB1), fmaxf(mB2, mB3));
            mlocA = fmaxf(mlocA, __shfl_xor(mlocA, 16));
            mlocA = fmaxf(mlocA, __shfl_xor(mlocA, 32));
            mlocB = fmaxf(mlocB, __shfl_xor(mlocB, 16));
            mlocB = fmaxf(mlocB, __shfl_xor(mlocB, 32));

            // ---- defer-max: rescale only when max grew past threshold ----
            if (!__all(mlocA <= mrunA + THR_RAW)) {
                const float mnewA = fmaxf(mrunA, mlocA);
                const float alphaA = __builtin_amdgcn_exp2f((mrunA - mnewA) * C2LOG);
                mrunA = mnewA;
                lrunA *= alphaA;
                #pragma unroll
                for (int c = 0; c < 4; ++c)
                    #pragma unroll
                    for (int r = 0; r < 4; ++r) oA[c][r] *= alphaA;
            }
            if (!__all(mlocB <= mrunB + THR_RAW)) {
                const float mnewB = fmaxf(mrunB, mlocB);
                const float alphaB = __builtin_amdgcn_exp2f((mrunB - mnewB) * C2LOG);
                mrunB = mnewB;
                lrunB *= alphaB;
                #pragma unroll
                for (int c = 0; c < 4; ++c)
                    #pragma unroll
                    for (int r = 0; r < 4; ++r) oB[c][r] *= alphaB;
            }

            // ---- p = exp2(fma(st, C2LOG, -m*C2LOG)) ----
            const float ncA = -mrunA * C2LOG;
            const float ncB = -mrunB * C2LOG;
            float pA[4][4], pB[4][4];
            float rsA = 0.f, rsB = 0.f;
            #pragma unroll
            for (int kt = 0; kt < 4; ++kt)
                #pragma unroll
                for (int r = 0; r < 4; ++r) {
                    pA[kt][r] = __builtin_amdgcn_exp2f(__builtin_fmaf(stA[kt][r], C2LOG, ncA));
                    rsA += pA[kt][r];
                    pB[kt][r] = __builtin_amdgcn_exp2f(__builtin_fmaf(stB[kt][r], C2LOG, ncB));
                    rsB += pB[kt][r];
                }
            rsA += __shfl_xor(rsA, 16); rsA += __shfl_xor(rsA, 32);
            rsB += __shfl_xor(rsB, 16); rsB += __shfl_xor(rsB, 32);
            lrunA += rsA;
            lrunB += rsB;

            // ---- pack P^T to bf16 pairs (HW cvt_pk) ----
            unsigned uA[4][2], uB[4][2];
            #pragma unroll
            for (int kt = 0; kt < 4; ++kt) {
                uA[kt][0] = cvtpk(pA[kt][0], pA[kt][1]);
                uA[kt][1] = cvtpk(pA[kt][2], pA[kt][3]);
                uB[kt][0] = cvtpk(pB[kt][0], pB[kt][1]);
                uB[kt][1] = cvtpk(pB[kt][2], pB[kt][3]);
            }

            // ---- PV: both sub-tiles share va reads ----
            #pragma unroll
            for (int h = 0; h < 2; ++h) {
                const int a0 = __shfl((int)uA[2*h][0],   srcA);
                const int a1c = __shfl((int)uA[2*h+1][0], srcA);
                const int a2 = __shfl((int)uA[2*h][1],   srcA);
                const int a3c = __shfl((int)uA[2*h+1][1], srcA);
                const int a4 = __shfl((int)uA[2*h][0],   srcB);
                const int a5c = __shfl((int)uA[2*h+1][0], srcB);
                const int a6 = __shfl((int)uA[2*h][1],   srcB);
                const int a7c = __shfl((int)uA[2*h+1][1], srcB);
                union { i32x4 iv; bf16x8 v; } cvA;
                cvA.iv = i32x4{ hihalf ? a1c : a0, hihalf ? a3c : a2,
                                hihalf ? a5c : a4, hihalf ? a7c : a6 };
                const int b0 = __shfl((int)uB[2*h][0],   srcA);
                const int b1c = __shfl((int)uB[2*h+1][0], srcA);
                const int b2 = __shfl((int)uB[2*h][1],   srcA);
                const int b3c = __shfl((int)uB[2*h+1][1], srcA);
                const int b4 = __shfl((int)uB[2*h][0],   srcB);
                const int b5c = __shfl((int)uB[2*h+1][0], srcB);
                const int b6 = __shfl((int)uB[2*h][1],   srcB);
                const int b7c = __shfl((int)uB[2*h+1][1], srcB);
                union { i32x4 iv; bf16x8 v; } cvB;
                cvB.iv = i32x4{ hihalf ? b1c : b0, hihalf ? b3c : b2,
                                hihalf ? b5c : b4, hihalf ? b7c : b6 };
                __builtin_amdgcn_s_setprio(1);
                #pragma unroll
                for (int c = 0; c < 4; ++c) {
                    const int vrow = c * 16 + lm;
                    const int sw = (vrow & 7) << 4;
                    bf16x8 va = *reinterpret_cast<const bf16x8*>(
                        (const char*)vsb + vrow * 128 + ((h * 64 + lg * 16) ^ sw));
                    oA[c] = __builtin_amdgcn_mfma_f32_16x16x32_bf16(va, cvA.v, oA[c], 0, 0, 0);
                    oB[c] = __builtin_amdgcn_mfma_f32_16x16x32_bf16(va, cvB.v, oB[c], 0, 0, 0);
                }
                __builtin_amdgcn_s_setprio(0);
            }
        }

        // ---- counted drain: wait only for next-needed buffer's stage ----
        __builtin_amdgcn_sched_barrier(0);
        asm volatile("s_waitcnt lgkmcnt(0)" ::: "memory");
        if (stage2) asm volatile("s_waitcnt vmcnt(4)" ::: "memory");
        else        asm volatile("s_waitcnt vmcnt(0)" ::: "memory");
        __builtin_amdgcn_s_barrier();
    }
#undef STAGE_KV

    // ---- write partials: O bf16 (task,row,d), m (RAW)/l fp32 ----
    short* Ob = Opart + (size_t)task * (128 * HD);
    #pragma unroll
    for (int c = 0; c < 4; ++c) {
        int2 pkA, pkB;
        pkA.x = (int)cvtpk(oA[c][0], oA[c][1]);
        pkA.y = (int)cvtpk(oA[c][2], oA[c][3]);
        pkB.x = (int)cvtpk(oB[c][0], oB[c][1]);
        pkB.y = (int)cvtpk(oB[c][2], oB[c][3]);
        *reinterpret_cast<int2*>(&Ob[(wv * 32 + lm) * HD + c * 16 + lg * 4]) = pkA;
        *reinterpret_cast<int2*>(&Ob[(wv * 32 + 16 + lm) * HD + c * 16 + lg * 4]) = pkB;
    }
    if (lg == 0) {
        Mpart[task * 128 + wv * 32 + lm] = mrunA;
        Lpart[task * 128 + wv * 32 + lm] = lrunA;
        Mpart[task * 128 + wv * 32 + 16 + lm] = mrunB;
        Lpart[task * 128 + wv * 32 + 16 + lm] = lrunB;
    }
}

// =====================================================================
// Kernel 4: combine partials -> fp32 out (Mpart RAW units).
// =====================================================================
__global__ __launch_bounds__(256) void combine(const short* __restrict__ Opart,
        const float* __restrict__ Mpart, const float* __restrict__ Lpart,
        float* __restrict__ out) {
    const int b   = blockIdx.x >> 8;
    const int rem = blockIdx.x & 255;
    const int i   = rem >> 3;
    const int rr  = rem & 7;
    const int g = i >> 2;
    const int S = g + 1;
    const int task0 = b * NTASK_PB + 2 * g * (g + 1) + (i - 4 * g) * (g + 1);
    const int qbase = i * 128;

    const int tid = threadIdx.x;
    const int row = rr * 16 + (tid >> 4);   // 0..127
    const int cb  = (tid & 15) << 2;        // col (x4 floats)

    float mmax = -1e30f;
    float ms[8];
    for (int s = 0; s < S; ++s) {
        ms[s] = Mpart[(task0 + s) * 128 + row];
        mmax = fmaxf(mmax, ms[s]);
    }
    float lsum = 0.f;
    float a0 = 0.f, a1 = 0.f, a2 = 0.f, a3 = 0.f;
    for (int s = 0; s < S; ++s) {
        const float w = __builtin_amdgcn_exp2f((ms[s] - mmax) * C2LOG);
        lsum += Lpart[(task0 + s) * 128 + row] * w;
        bf16x4 ov = *reinterpret_cast<const bf16x4*>(
            &Opart[((size_t)(task0 + s) * 128 + row) * HD + cb]);
        a0 += bf2f(ov[0]) * w;
        a1 += bf2f(ov[1]) * w;
        a2 += bf2f(ov[2]) * w;
        a3 += bf2f(ov[3]) * w;
    }
    const float inv = 1.0f / lsum;
    f32x4 res{ a0 * inv, a1 * inv, a2 * inv, a3 * inv };
    *reinterpret_cast<f32x4*>(
        &out[((size_t)b * TT + qbase + row) * HD + cb]) = res;
}

// =====================================================================
extern "C" void kernel_launch(void* const* d_in, const int* in_sizes, int n_in,
                              void* d_out, int out_size, void* d_ws, size_t ws_size,
                              hipStream_t stream) {
    const float* x  = (const float*)d_in[0];
    const float* Wq = (const float*)d_in[1];
    const float* Wk = (const float*)d_in[2];
    const float* Wv = (const float*)d_in[3];
    float* out = (float*)d_out;

    char* ws = (char*)d_ws;
    short* Wt    = (short*)(ws);                          // 393216 B
    short* Q     = (short*)(ws + 393216);                 // 2097152 B
    short* K     = (short*)(ws + 2490368);                // 2097152 B
    short* Vt    = (short*)(ws + 4587520);                // 2097152 B
    short* Opart = (short*)(ws + 6684672);                // 9437184 B
    float* Mpart = (float*)(ws + 16121856);               // 294912 B
    float* Lpart = (float*)(ws + 16416768);               // 294912 B

    hipLaunchKernelGGL(prep_w,   dim3(48),    dim3(256), 0, stream, Wq, Wk, Wv, Wt);
    hipLaunchKernelGGL(proj_qkv, dim3(512),   dim3(512), 0, stream, x, Wt, Q, K, Vt);
    hipLaunchKernelGGL(attn,     dim3(NTASK), dim3(256), 0, stream, Q, K, Vt,
                       Opart, Mpart, Lpart);
    hipLaunchKernelGGL(combine,  dim3(1024),  dim3(256), 0, stream,
                       Opart, Mpart, Lpart, out);
}